// Round 5
// baseline (879.835 us; speedup 1.0000x reference)
//
#include <hip/hip_runtime.h>

#define B_ 4
#define H_ 16
#define D_ 64
#define E_ 1024
#define SQ_ 2048
#define SKV_ 2049
#define SKVP_ 2080

typedef __attribute__((ext_vector_type(8))) short short8;
typedef __attribute__((ext_vector_type(4))) float f32x4;
typedef __attribute__((ext_vector_type(16))) float f32x16;
typedef __attribute__((ext_vector_type(4))) unsigned int u32x4;

static __device__ __forceinline__ unsigned short f2bf(float f) {
    unsigned int u = __float_as_uint(f);
    u += 0x7FFFu + ((u >> 16) & 1u);
    return (unsigned short)(u >> 16);
}
static __device__ __forceinline__ unsigned int pack2(float a, float b) {
    return (unsigned int)f2bf(a) | ((unsigned int)f2bf(b) << 16);
}

static __device__ __forceinline__ f32x4 mfma16(short8 a, short8 b, f32x4 c) {
    return __builtin_amdgcn_mfma_f32_16x16x32_bf16(a, b, c, 0, 0, 0);
}
static __device__ __forceinline__ f32x16 mfma32(short8 a, short8 b, f32x16 c) {
    return __builtin_amdgcn_mfma_f32_32x32x16_bf16(a, b, c, 0, 0, 0);
}

// ---------------------------------------------------------------------------
// Mask decode: sniff dtype (uint8 bool vs int32/f32 0/1 words), write uint8.
// ---------------------------------------------------------------------------
__global__ void decode_mask_kernel(const void* __restrict__ mraw,
                                   unsigned char* __restrict__ condm) {
    __shared__ int flags[2];
    const int t = threadIdx.x;
    if (t < 2) flags[t] = 1;
    __syncthreads();
    const unsigned int* wp = (const unsigned int*)mraw;
    int okI = 1, okF = 1;
    for (int i = t; i < 2048; i += 256) {
        unsigned int w = wp[i];
        if (w > 1u) okI = 0;
        if (w != 0u && w != 0x3F800000u) okF = 0;
    }
    if (!okI) atomicAnd(&flags[0], 0);
    if (!okF) atomicAnd(&flags[1], 0);
    __syncthreads();
    const int isWord = flags[0] | flags[1];
    for (int i = t; i < B_ * SQ_; i += 256) {
        unsigned char v;
        if (isWord) v = (unsigned char)(wp[i] != 0u);
        else        v = (unsigned char)(((const unsigned char*)mraw)[i] != 0);
        condm[i] = v;
    }
}

// ---------------------------------------------------------------------------
// GEMM: C = A @ W^T + bias.  (MODE 0 additionally scales by 1/8 = 1/sqrt(64))
// ---------------------------------------------------------------------------
template <int MODE>
__global__ __launch_bounds__(256, 2)
void gemm_kernel(const void* __restrict__ Ain, const float* __restrict__ W,
                 const float* __restrict__ bias, void* __restrict__ Outp, int nrows) {
    __shared__ unsigned short As[64][40];
    __shared__ unsigned short Ws[64][40];
    const int t = threadIdx.x;
    const int row0 = blockIdx.x * 64;
    const int col0 = blockIdx.y * 64;
    const int w = t >> 6, lane = t & 63;
    const int wm = w >> 1, wn = w & 1;
    const int lr = lane & 15, lg = lane >> 4, lk = lg * 8;
    const int srow = t >> 2, sk = (t & 3) * 8;
    int arow = row0 + srow;
    if (arow >= nrows) arow = nrows - 1;
    const int wrow = col0 + srow;

    f32x4 acc[2][2] = {};

#pragma unroll 1
    for (int k0 = 0; k0 < E_; k0 += 32) {
        if constexpr (MODE == 3) {
            const unsigned short* A = (const unsigned short*)Ain;
            *(short8*)&As[srow][sk] = *(const short8*)&A[(size_t)arow * E_ + k0 + sk];
        } else {
            const float* A = (const float*)Ain;
            const float* ap = &A[(size_t)arow * E_ + k0 + sk];
            short8 v;
#pragma unroll
            for (int i = 0; i < 8; ++i) v[i] = (short)f2bf(ap[i]);
            *(short8*)&As[srow][sk] = v;
        }
        {
            const float* wpr = &W[(size_t)wrow * E_ + k0 + sk];
            short8 v;
#pragma unroll
            for (int i = 0; i < 8; ++i) v[i] = (short)f2bf(wpr[i]);
            *(short8*)&Ws[srow][sk] = v;
        }
        __syncthreads();
        short8 a0 = *(const short8*)&As[wm * 32 + lr][lk];
        short8 a1 = *(const short8*)&As[wm * 32 + 16 + lr][lk];
        short8 b0 = *(const short8*)&Ws[wn * 32 + lr][lk];
        short8 b1 = *(const short8*)&Ws[wn * 32 + 16 + lr][lk];
        acc[0][0] = mfma16(a0, b0, acc[0][0]);
        acc[0][1] = mfma16(a0, b1, acc[0][1]);
        acc[1][0] = mfma16(a1, b0, acc[1][0]);
        acc[1][1] = mfma16(a1, b1, acc[1][1]);
        __syncthreads();
    }

#pragma unroll
    for (int ni = 0; ni < 2; ++ni) {
        const int c = col0 + wn * 32 + ni * 16 + lr;
        const float bv = bias[c];
#pragma unroll
        for (int mi = 0; mi < 2; ++mi) {
#pragma unroll
            for (int r4 = 0; r4 < 4; ++r4) {
                const int r = row0 + wm * 32 + mi * 16 + lg * 4 + r4;
                if (r >= nrows) continue;
                float v = acc[mi][ni][r4] + bv;
                if constexpr (MODE == 0) {
                    v *= 0.125f;  // fold 1/sqrt(head_dim) into Q
                    const int sq = r >> 2, b = r & 3;
                    const int h = c >> 6, d = c & 63;
                    ((unsigned short*)Outp)[(((size_t)(b * H_ + h) * SQ_) + sq) * D_ + d] = f2bf(v);
                } else if constexpr (MODE == 1) {
                    const int kvi = r >> 2, b = r & 3;
                    const int h = c >> 6, d = c & 63;
                    ((unsigned short*)Outp)[(((size_t)(b * H_ + h) * SKVP_) + kvi) * D_ + d] = f2bf(v);
                } else if constexpr (MODE == 2) {
                    const int kvi = r >> 2, b = r & 3;
                    const int h = c >> 6, d = c & 63;
                    ((unsigned short*)Outp)[(((size_t)(b * H_ + h) * D_) + d) * SKVP_ + kvi] = f2bf(v);
                } else {
                    ((float*)Outp)[(size_t)r * E_ + c] = v;
                }
            }
        }
    }
}

// ---------------------------------------------------------------------------
// Zero the kv padding rows/cols (2049..2079) of K and V^T.
// ---------------------------------------------------------------------------
__global__ void zero_pad_kernel(unsigned short* __restrict__ Kb,
                                unsigned short* __restrict__ Vt) {
    const int idx = blockIdx.x * blockDim.x + threadIdx.x;
    const int NK = 64 * 31 * 64;
    if (idx < NK) {
        const int bh = idx / (31 * 64);
        const int rem = idx - bh * 31 * 64;
        const int kvi = SKV_ + rem / 64;
        const int d = rem & 63;
        Kb[((size_t)bh * SKVP_ + kvi) * D_ + d] = 0;
    } else {
        const int j = idx - NK;
        if (j < 4096 * 31) {
            const int row = j / 31;
            const int kvi = SKV_ + (j - row * 31);
            Vt[(size_t)row * SKVP_ + kvi] = 0;
        }
    }
}

// ---------------------------------------------------------------------------
// Flash attention fwd, swapped-operand 32x32 structure.
// Stores m and 1/l per (bh, q).
// ---------------------------------------------------------------------------
__global__ __launch_bounds__(256, 4)
void attn_fwd_kernel(const unsigned short* __restrict__ Qb, const unsigned short* __restrict__ Kb,
                     const unsigned short* __restrict__ Vt, const unsigned char* __restrict__ condm,
                     unsigned short* __restrict__ OP, float* __restrict__ Mst,
                     float* __restrict__ Lst) {
    const int h = blockIdx.y, b = blockIdx.z;
    const int bh = b * H_ + h;
    const int t = threadIdx.x, w = t >> 6, lane = t & 63;
    const int ql = lane & 31;
    const int hi = lane >> 5;
    const int qg = blockIdx.x * 128 + w * 32 + ql;

    __shared__ unsigned short Ks[32 * 64];   // XOR-swizzled, 16B granules
    __shared__ unsigned short Vs[64][40];    // padded rows (2-way only)
    __shared__ unsigned int cjb[65];

    for (int g = t; g < 65; g += 256) {
        unsigned int wbits = 0;
        const int base = g * 32;
#pragma unroll 4
        for (int i = 0; i < 32; ++i) {
            const int kv = base + i;
            if (kv >= 1 && kv < SKV_) wbits |= ((unsigned int)condm[b * SQ_ + kv - 1]) << i;
        }
        cjb[g] = wbits;
    }

    const size_t qoff = ((size_t)bh * SQ_ + qg) * D_;
    short8 qf[4];
#pragma unroll
    for (int tt = 0; tt < 4; ++tt) qf[tt] = *(const short8*)&Qb[qoff + tt * 16 + hi * 8];

    const unsigned int ci = condm[b * SQ_ + qg];

    float m = -__builtin_inff(), l = 0.f;
    f32x16 o0 = {}, o1 = {};

    const int krow = t >> 3, kseg = t & 7;
    const int vrow = t >> 2, vpart = t & 3;
    const unsigned short* Kbase = &Kb[(size_t)bh * SKVP_ * D_];
    const unsigned short* Vbase = &Vt[(size_t)bh * D_ * SKVP_];

#pragma unroll 1
    for (int kv0 = 0; kv0 < SKVP_; kv0 += 32) {
        __syncthreads();
        *(short8*)&Ks[krow * 64 + ((kseg ^ (krow & 7)) * 8)] =
            *(const short8*)&Kbase[(size_t)(kv0 + krow) * D_ + kseg * 8];
        *(short8*)&Vs[vrow][vpart * 8] =
            *(const short8*)&Vbase[(size_t)vrow * SKVP_ + kv0 + vpart * 8];
        __syncthreads();

        // S^T = K @ Q^T  (col = q = ql, row = k)
        f32x16 S = {};
#pragma unroll
        for (int tt = 0; tt < 4; ++tt) {
            const short8 kf = *(const short8*)&Ks[ql * 64 + (((2 * tt + hi) ^ (ql & 7)) * 8)];
            S = mfma32(kf, qf[tt], S);
        }

        // mask bits: bit i => kv0+i masked for this q-row
        const unsigned int cjw = cjb[kv0 >> 5];
        const int T = qg + 1 - kv0;
        unsigned int causalw;
        if (T < 0) causalw = ~0u;
        else if (T >= 31) causalw = 0u;
        else causalw = (~0u) << (T + 1);
        unsigned int mb = ci ? ~cjw : causalw;
        if (kv0 == 0) mb &= ~1u;     // text column always visible
        const unsigned int mbs = mb >> (hi * 4);

        float rmax = -__builtin_inff();
#pragma unroll
        for (int r = 0; r < 16; ++r) {
            const int kc = (r & 3) + 8 * (r >> 2);
            const float s = ((mbs >> kc) & 1u) ? -__builtin_inff() : S[r];
            S[r] = s;
            rmax = fmaxf(rmax, s);
        }
        rmax = fmaxf(rmax, __shfl_xor(rmax, 32));
        const float mn = fmaxf(m, rmax);
        float psum = 0.f;
#pragma unroll
        for (int r = 0; r < 16; ++r) {
            const float p = __expf(S[r] - mn);   // exp(-inf)=0 for masked
            S[r] = p;
            psum += p;
        }
        psum += __shfl_xor(psum, 32);
        const float alpha = __expf(m - mn);
        l = l * alpha + psum;
        m = mn;
        o0 *= alpha;
        o1 *= alpha;

        // pack P pairs to bf16 words (k = crow pairs)
        const unsigned int w0 = pack2(S[0], S[1]);
        const unsigned int w1 = pack2(S[2], S[3]);
        const unsigned int w2 = pack2(S[4], S[5]);
        const unsigned int w3 = pack2(S[6], S[7]);
        const unsigned int w4 = pack2(S[8], S[9]);
        const unsigned int w5 = pack2(S[10], S[11]);
        const unsigned int w6 = pack2(S[12], S[13]);
        const unsigned int w7 = pack2(S[14], S[15]);
        // partner-half copies
        const unsigned int x0 = __shfl_xor(w0, 32);
        const unsigned int x1 = __shfl_xor(w1, 32);
        const unsigned int x2 = __shfl_xor(w2, 32);
        const unsigned int x3 = __shfl_xor(w3, 32);
        const unsigned int x4 = __shfl_xor(w4, 32);
        const unsigned int x5 = __shfl_xor(w5, 32);
        const unsigned int x6 = __shfl_xor(w6, 32);
        const unsigned int x7 = __shfl_xor(w7, 32);
        union { u32x4 u; short8 s8; } pb0, pb1;
        pb0.u = (u32x4){hi ? x2 : w0, hi ? x3 : w1, hi ? w2 : x0, hi ? w3 : x1};
        pb1.u = (u32x4){hi ? x6 : w4, hi ? x7 : w5, hi ? w6 : x4, hi ? w7 : x5};

        // O^T += V^T @ P^T  (col = q, row = d)
        const short8 vf00 = *(const short8*)&Vs[ql][hi * 8];
        const short8 vf01 = *(const short8*)&Vs[ql][16 + hi * 8];
        const short8 vf10 = *(const short8*)&Vs[32 + ql][hi * 8];
        const short8 vf11 = *(const short8*)&Vs[32 + ql][16 + hi * 8];
        o0 = mfma32(vf00, pb0.s8, o0);
        o0 = mfma32(vf01, pb1.s8, o0);
        o1 = mfma32(vf10, pb0.s8, o1);
        o1 = mfma32(vf11, pb1.s8, o1);
    }

    const float linv = 1.0f / l;
    unsigned short* opbase = &OP[((size_t)qg * B_ + b) * E_ + h * D_];
#pragma unroll
    for (int rp = 0; rp < 8; ++rp) {
        const int r0 = rp * 2, r1 = r0 + 1;
        const int d = ((r0 & 3) + 8 * (r0 >> 2)) + 4 * hi;
        *(unsigned int*)(opbase + d) = pack2(o0[r0] * linv, o0[r1] * linv);
        *(unsigned int*)(opbase + 32 + d) = pack2(o1[r0] * linv, o1[r1] * linv);
    }
    if (hi == 0) {
        Mst[(size_t)bh * SQ_ + qg] = m;
        Lst[(size_t)bh * SQ_ + qg] = linv;   // store 1/l
    }
}

// ---------------------------------------------------------------------------
// attn-mean pass, swapped-operand 32x32: block = (kv-tile 64) x (q-tile 128).
// Lane owns q = qbase + (lane&31); loops h; accumulates sum_h P/16.
// ---------------------------------------------------------------------------
__global__ __launch_bounds__(256, 2)
void attn_probs_kernel(const unsigned short* __restrict__ Qb, const unsigned short* __restrict__ Kb,
                       const float* __restrict__ Mst, const float* __restrict__ Linv,
                       const unsigned char* __restrict__ condm, float* __restrict__ out1) {
    const int kv0 = blockIdx.x * 64;
    const int b = blockIdx.z;
    const int t = threadIdx.x, w = t >> 6, lane = t & 63;
    const int ql = lane & 31, hi = lane >> 5;
    const int qg = blockIdx.y * 128 + w * 32 + ql;

    __shared__ unsigned short Ks[64 * 64];   // XOR-swizzled, 16B granules
    __shared__ float Tr[4][32 * 33];         // per-wave transpose buffer
    __shared__ unsigned int cjw2[2];

    // cj bit words for the block's two 32-k groups (one ballot in wave 0)
    if (t < 64) {
        const int kvv = kv0 + t;
        int pred = 0;
        if (kvv >= 1 && kvv < SKV_) pred = condm[b * SQ_ + kvv - 1];
        const unsigned long long bal = __ballot(pred != 0);
        if (t == 0) { cjw2[0] = (unsigned int)bal; cjw2[1] = (unsigned int)(bal >> 32); }
    }
    const unsigned int ci = condm[b * SQ_ + qg];
    __syncthreads();

    // per-lane mask words (already shifted by hi*4)
    unsigned int mbs[2];
#pragma unroll
    for (int kt = 0; kt < 2; ++kt) {
        const int kvg = kv0 + kt * 32;
        const unsigned int cjw = cjw2[kt];
        const int T = qg + 1 - kvg;
        unsigned int causalw;
        if (T < 0) causalw = ~0u;
        else if (T >= 31) causalw = 0u;
        else causalw = (~0u) << (T + 1);
        unsigned int mb = ci ? ~cjw : causalw;
        if (kvg == 0) mb &= ~1u;             // text column always visible
        const int nvalid = SKV_ - kvg;       // k >= SKV are invalid
        if (nvalid <= 0) mb = ~0u;
        else if (nvalid < 32) mb |= ((~0u) << nvalid);
        mbs[kt] = mb >> (hi * 4);
    }

    const int krow = t >> 2;                 // 0..63
    const int kseg2 = (t & 3) * 2;           // segment pair
    int ksrc = kv0 + krow;
    if (ksrc >= SKVP_) ksrc = SKVP_ - 1;     // clamp (rows >= SKV all masked)

    float acc[2][16] = {};

#pragma unroll 1
    for (int h = 0; h < H_; ++h) {
        const int bh = b * H_ + h;
        __syncthreads();
        {
            const unsigned short* kp = &Kb[((size_t)bh * SKVP_ + ksrc) * D_];
            *(short8*)&Ks[krow * 64 + ((kseg2 ^ (krow & 7)) * 8)] = *(const short8*)&kp[kseg2 * 8];
            *(short8*)&Ks[krow * 64 + (((kseg2 + 1) ^ (krow & 7)) * 8)] = *(const short8*)&kp[(kseg2 + 1) * 8];
        }
        __syncthreads();

        const size_t qoff = ((size_t)bh * SQ_ + qg) * D_;
        short8 qf[4];
#pragma unroll
        for (int tt = 0; tt < 4; ++tt) qf[tt] = *(const short8*)&Qb[qoff + tt * 16 + hi * 8];
        const float mh = Mst[(size_t)bh * SQ_ + qg];
        const float li = Linv[(size_t)bh * SQ_ + qg];

#pragma unroll
        for (int kt = 0; kt < 2; ++kt) {
            f32x16 S = {};
#pragma unroll
            for (int tt = 0; tt < 4; ++tt) {
                const short8 kf = *(const short8*)&Ks[(kt * 32 + ql) * 64 + (((2 * tt + hi) ^ (ql & 7)) * 8)];
                S = mfma32(kf, qf[tt], S);
            }
#pragma unroll
            for (int r = 0; r < 16; ++r) {
                const int kc = (r & 3) + 8 * (r >> 2);
                const float p = ((mbs[kt] >> kc) & 1u) ? 0.f : __expf(S[r] - mh);
                acc[kt][r] += p * li;
            }
        }
    }

    // epilogue: transpose via per-wave LDS, coalesced scalar stores
    const float inv16 = 1.0f / 16.0f;
    const int qb_w = blockIdx.y * 128 + w * 32;
#pragma unroll 1
    for (int kt = 0; kt < 2; ++kt) {
#pragma unroll
        for (int r = 0; r < 16; ++r) {
            const int kc = (r & 3) + 8 * (r >> 2) + 4 * hi;
            Tr[w][ql * 33 + kc] = acc[kt][r] * inv16;
        }
        const int kcol = kv0 + kt * 32 + ql;
        const bool kok = (kcol < SKV_);
#pragma unroll
        for (int step = 0; step < 16; ++step) {
            const int q2 = step * 2 + hi;
            const float v = Tr[w][q2 * 33 + ql];
            if (kok) out1[((size_t)b * SQ_ + qb_w + q2) * SKV_ + kcol] = v;
        }
    }
}

// ---------------------------------------------------------------------------
extern "C" void kernel_launch(void* const* d_in, const int* in_sizes, int n_in,
                              void* d_out, int out_size, void* d_ws, size_t ws_size,
                              hipStream_t stream) {
    const float* q   = (const float*)d_in[0];
    const float* kv  = (const float*)d_in[1];
    const void*  msk = d_in[2];
    const float* Wq  = (const float*)d_in[3];
    const float* bq  = (const float*)d_in[4];
    const float* Wk  = (const float*)d_in[5];
    const float* bk  = (const float*)d_in[6];
    const float* Wv  = (const float*)d_in[7];
    const float* bv  = (const float*)d_in[8];
    const float* Wo  = (const float*)d_in[9];
    const float* bo  = (const float*)d_in[10];

    char* ws = (char*)d_ws;
    unsigned short* Qb  = (unsigned short*)(ws);              // 16,777,216 B
    unsigned short* Kb  = (unsigned short*)(ws + 16777216);   // 17,039,360 B
    unsigned short* Vt  = (unsigned short*)(ws + 33816576);   // 17,039,360 B
    unsigned short* OP  = (unsigned short*)(ws + 50855936);   // 16,777,216 B
    float*          Mst = (float*)(ws + 67633152);            //    524,288 B
    float*          Lst = (float*)(ws + 68157440);            //    524,288 B
    unsigned char* condm = (unsigned char*)(ws + 68681728);   //      8,192 B

    float* out0 = (float*)d_out;
    float* out1 = out0 + (size_t)SQ_ * B_ * E_;

    decode_mask_kernel<<<1, 256, 0, stream>>>(msk, condm);
    gemm_kernel<0><<<dim3(128, 16), 256, 0, stream>>>((const void*)q, Wq, bq, (void*)Qb, SQ_ * B_);
    gemm_kernel<1><<<dim3(129, 16), 256, 0, stream>>>((const void*)kv, Wk, bk, (void*)Kb, SKV_ * B_);
    gemm_kernel<2><<<dim3(129, 16), 256, 0, stream>>>((const void*)kv, Wv, bv, (void*)Vt, SKV_ * B_);
    zero_pad_kernel<<<992, 256, 0, stream>>>(Kb, Vt);
    attn_fwd_kernel<<<dim3(16, 16, 4), 256, 0, stream>>>(Qb, Kb, Vt, condm, OP, Mst, Lst);
    attn_probs_kernel<<<dim3(33, 16, 4), 256, 0, stream>>>(Qb, Kb, Mst, Lst, condm, out1);
    gemm_kernel<3><<<dim3(128, 16), 256, 0, stream>>>((const void*)OP, Wo, bo, (void*)out0, SQ_ * B_);
}

// Round 6
// 597.736 us; speedup vs baseline: 1.4719x; 1.4719x over previous
//
#include <hip/hip_runtime.h>

#define B_ 4
#define H_ 16
#define D_ 64
#define E_ 1024
#define SQ_ 2048
#define SKV_ 2049
#define SKVP_ 2080

typedef __attribute__((ext_vector_type(8))) short short8;
typedef __attribute__((ext_vector_type(4))) float f32x4;
typedef __attribute__((ext_vector_type(16))) float f32x16;
typedef __attribute__((ext_vector_type(4))) unsigned int u32x4;

static __device__ __forceinline__ unsigned short f2bf(float f) {
    unsigned int u = __float_as_uint(f);
    u += 0x7FFFu + ((u >> 16) & 1u);
    return (unsigned short)(u >> 16);
}
static __device__ __forceinline__ unsigned int pack2(float a, float b) {
    return (unsigned int)f2bf(a) | ((unsigned int)f2bf(b) << 16);
}

static __device__ __forceinline__ f32x4 mfma16(short8 a, short8 b, f32x4 c) {
    return __builtin_amdgcn_mfma_f32_16x16x32_bf16(a, b, c, 0, 0, 0);
}
static __device__ __forceinline__ f32x16 mfma32(short8 a, short8 b, f32x16 c) {
    return __builtin_amdgcn_mfma_f32_32x32x16_bf16(a, b, c, 0, 0, 0);
}

// ---------------------------------------------------------------------------
// Mask decode: sniff dtype (uint8 bool vs int32/f32 0/1 words), write uint8.
// ---------------------------------------------------------------------------
__global__ void decode_mask_kernel(const void* __restrict__ mraw,
                                   unsigned char* __restrict__ condm) {
    __shared__ int flags[2];
    const int t = threadIdx.x;
    if (t < 2) flags[t] = 1;
    __syncthreads();
    const unsigned int* wp = (const unsigned int*)mraw;
    int okI = 1, okF = 1;
    for (int i = t; i < 2048; i += 256) {
        unsigned int w = wp[i];
        if (w > 1u) okI = 0;
        if (w != 0u && w != 0x3F800000u) okF = 0;
    }
    if (!okI) atomicAnd(&flags[0], 0);
    if (!okF) atomicAnd(&flags[1], 0);
    __syncthreads();
    const int isWord = flags[0] | flags[1];
    for (int i = t; i < B_ * SQ_; i += 256) {
        unsigned char v;
        if (isWord) v = (unsigned char)(wp[i] != 0u);
        else        v = (unsigned char)(((const unsigned char*)mraw)[i] != 0);
        condm[i] = v;
    }
}

// ---------------------------------------------------------------------------
// GEMM: C = A @ W^T + bias.  (MODE 0 additionally scales by 1/8 = 1/sqrt(64))
// ---------------------------------------------------------------------------
template <int MODE>
__global__ __launch_bounds__(256, 2)
void gemm_kernel(const void* __restrict__ Ain, const float* __restrict__ W,
                 const float* __restrict__ bias, void* __restrict__ Outp, int nrows) {
    __shared__ unsigned short As[64][40];
    __shared__ unsigned short Ws[64][40];
    const int t = threadIdx.x;
    const int row0 = blockIdx.x * 64;
    const int col0 = blockIdx.y * 64;
    const int w = t >> 6, lane = t & 63;
    const int wm = w >> 1, wn = w & 1;
    const int lr = lane & 15, lg = lane >> 4, lk = lg * 8;
    const int srow = t >> 2, sk = (t & 3) * 8;
    int arow = row0 + srow;
    if (arow >= nrows) arow = nrows - 1;
    const int wrow = col0 + srow;

    f32x4 acc[2][2] = {};

#pragma unroll 1
    for (int k0 = 0; k0 < E_; k0 += 32) {
        if constexpr (MODE == 3) {
            const unsigned short* A = (const unsigned short*)Ain;
            *(short8*)&As[srow][sk] = *(const short8*)&A[(size_t)arow * E_ + k0 + sk];
        } else {
            const float* A = (const float*)Ain;
            const float* ap = &A[(size_t)arow * E_ + k0 + sk];
            short8 v;
#pragma unroll
            for (int i = 0; i < 8; ++i) v[i] = (short)f2bf(ap[i]);
            *(short8*)&As[srow][sk] = v;
        }
        {
            const float* wpr = &W[(size_t)wrow * E_ + k0 + sk];
            short8 v;
#pragma unroll
            for (int i = 0; i < 8; ++i) v[i] = (short)f2bf(wpr[i]);
            *(short8*)&Ws[srow][sk] = v;
        }
        __syncthreads();
        short8 a0 = *(const short8*)&As[wm * 32 + lr][lk];
        short8 a1 = *(const short8*)&As[wm * 32 + 16 + lr][lk];
        short8 b0 = *(const short8*)&Ws[wn * 32 + lr][lk];
        short8 b1 = *(const short8*)&Ws[wn * 32 + 16 + lr][lk];
        acc[0][0] = mfma16(a0, b0, acc[0][0]);
        acc[0][1] = mfma16(a0, b1, acc[0][1]);
        acc[1][0] = mfma16(a1, b0, acc[1][0]);
        acc[1][1] = mfma16(a1, b1, acc[1][1]);
        __syncthreads();
    }

#pragma unroll
    for (int ni = 0; ni < 2; ++ni) {
        const int c = col0 + wn * 32 + ni * 16 + lr;
        const float bv = bias[c];
#pragma unroll
        for (int mi = 0; mi < 2; ++mi) {
#pragma unroll
            for (int r4 = 0; r4 < 4; ++r4) {
                const int r = row0 + wm * 32 + mi * 16 + lg * 4 + r4;
                if (r >= nrows) continue;
                float v = acc[mi][ni][r4] + bv;
                if constexpr (MODE == 0) {
                    v *= 0.125f;  // fold 1/sqrt(head_dim) into Q
                    const int sq = r >> 2, b = r & 3;
                    const int h = c >> 6, d = c & 63;
                    ((unsigned short*)Outp)[(((size_t)(b * H_ + h) * SQ_) + sq) * D_ + d] = f2bf(v);
                } else if constexpr (MODE == 1) {
                    const int kvi = r >> 2, b = r & 3;
                    const int h = c >> 6, d = c & 63;
                    ((unsigned short*)Outp)[(((size_t)(b * H_ + h) * SKVP_) + kvi) * D_ + d] = f2bf(v);
                } else if constexpr (MODE == 2) {
                    const int kvi = r >> 2, b = r & 3;
                    const int h = c >> 6, d = c & 63;
                    ((unsigned short*)Outp)[(((size_t)(b * H_ + h) * D_) + d) * SKVP_ + kvi] = f2bf(v);
                } else {
                    ((float*)Outp)[(size_t)r * E_ + c] = v;
                }
            }
        }
    }
}

// ---------------------------------------------------------------------------
// Zero the kv padding rows/cols (2049..2079) of K and V^T.
// ---------------------------------------------------------------------------
__global__ void zero_pad_kernel(unsigned short* __restrict__ Kb,
                                unsigned short* __restrict__ Vt) {
    const int idx = blockIdx.x * blockDim.x + threadIdx.x;
    const int NK = 64 * 31 * 64;
    if (idx < NK) {
        const int bh = idx / (31 * 64);
        const int rem = idx - bh * 31 * 64;
        const int kvi = SKV_ + rem / 64;
        const int d = rem & 63;
        Kb[((size_t)bh * SKVP_ + kvi) * D_ + d] = 0;
    } else {
        const int j = idx - NK;
        if (j < 4096 * 31) {
            const int row = j / 31;
            const int kvi = SKV_ + (j - row * 31);
            Vt[(size_t)row * SKVP_ + kvi] = 0;
        }
    }
}

// ---------------------------------------------------------------------------
// Flash attention fwd, swapped-operand 32x32 structure.
// Stores m and 1/l per (bh, q).
// ---------------------------------------------------------------------------
__global__ __launch_bounds__(256, 4)
void attn_fwd_kernel(const unsigned short* __restrict__ Qb, const unsigned short* __restrict__ Kb,
                     const unsigned short* __restrict__ Vt, const unsigned char* __restrict__ condm,
                     unsigned short* __restrict__ OP, float* __restrict__ Mst,
                     float* __restrict__ Lst) {
    const int h = blockIdx.y, b = blockIdx.z;
    const int bh = b * H_ + h;
    const int t = threadIdx.x, w = t >> 6, lane = t & 63;
    const int ql = lane & 31;
    const int hi = lane >> 5;
    const int qg = blockIdx.x * 128 + w * 32 + ql;

    __shared__ unsigned short Ks[32 * 64];   // XOR-swizzled, 16B granules
    __shared__ unsigned short Vs[64][40];    // padded rows (2-way only)
    __shared__ unsigned int cjb[65];

    for (int g = t; g < 65; g += 256) {
        unsigned int wbits = 0;
        const int base = g * 32;
#pragma unroll 4
        for (int i = 0; i < 32; ++i) {
            const int kv = base + i;
            if (kv >= 1 && kv < SKV_) wbits |= ((unsigned int)condm[b * SQ_ + kv - 1]) << i;
        }
        cjb[g] = wbits;
    }

    const size_t qoff = ((size_t)bh * SQ_ + qg) * D_;
    short8 qf[4];
#pragma unroll
    for (int tt = 0; tt < 4; ++tt) qf[tt] = *(const short8*)&Qb[qoff + tt * 16 + hi * 8];

    const unsigned int ci = condm[b * SQ_ + qg];

    float m = -__builtin_inff(), l = 0.f;
    f32x16 o0 = {}, o1 = {};

    const int krow = t >> 3, kseg = t & 7;
    const int vrow = t >> 2, vpart = t & 3;
    const unsigned short* Kbase = &Kb[(size_t)bh * SKVP_ * D_];
    const unsigned short* Vbase = &Vt[(size_t)bh * D_ * SKVP_];

#pragma unroll 1
    for (int kv0 = 0; kv0 < SKVP_; kv0 += 32) {
        __syncthreads();
        *(short8*)&Ks[krow * 64 + ((kseg ^ (krow & 7)) * 8)] =
            *(const short8*)&Kbase[(size_t)(kv0 + krow) * D_ + kseg * 8];
        *(short8*)&Vs[vrow][vpart * 8] =
            *(const short8*)&Vbase[(size_t)vrow * SKVP_ + kv0 + vpart * 8];
        __syncthreads();

        // S^T = K @ Q^T  (col = q = ql, row = k)
        f32x16 S = {};
#pragma unroll
        for (int tt = 0; tt < 4; ++tt) {
            const short8 kf = *(const short8*)&Ks[ql * 64 + (((2 * tt + hi) ^ (ql & 7)) * 8)];
            S = mfma32(kf, qf[tt], S);
        }

        // mask bits: bit i => kv0+i masked for this q-row
        const unsigned int cjw = cjb[kv0 >> 5];
        const int T = qg + 1 - kv0;
        unsigned int causalw;
        if (T < 0) causalw = ~0u;
        else if (T >= 31) causalw = 0u;
        else causalw = (~0u) << (T + 1);
        unsigned int mb = ci ? ~cjw : causalw;
        if (kv0 == 0) mb &= ~1u;     // text column always visible
        const unsigned int mbs = mb >> (hi * 4);

        float rmax = -__builtin_inff();
#pragma unroll
        for (int r = 0; r < 16; ++r) {
            const int kc = (r & 3) + 8 * (r >> 2);
            const float s = ((mbs >> kc) & 1u) ? -__builtin_inff() : S[r];
            S[r] = s;
            rmax = fmaxf(rmax, s);
        }
        rmax = fmaxf(rmax, __shfl_xor(rmax, 32));
        const float mn = fmaxf(m, rmax);
        float psum = 0.f;
#pragma unroll
        for (int r = 0; r < 16; ++r) {
            const float p = __expf(S[r] - mn);   // exp(-inf)=0 for masked
            S[r] = p;
            psum += p;
        }
        psum += __shfl_xor(psum, 32);
        const float alpha = __expf(m - mn);
        l = l * alpha + psum;
        m = mn;
        o0 *= alpha;
        o1 *= alpha;

        // pack P pairs to bf16 words (k = crow pairs)
        const unsigned int w0 = pack2(S[0], S[1]);
        const unsigned int w1 = pack2(S[2], S[3]);
        const unsigned int w2 = pack2(S[4], S[5]);
        const unsigned int w3 = pack2(S[6], S[7]);
        const unsigned int w4 = pack2(S[8], S[9]);
        const unsigned int w5 = pack2(S[10], S[11]);
        const unsigned int w6 = pack2(S[12], S[13]);
        const unsigned int w7 = pack2(S[14], S[15]);
        // partner-half copies
        const unsigned int x0 = __shfl_xor(w0, 32);
        const unsigned int x1 = __shfl_xor(w1, 32);
        const unsigned int x2 = __shfl_xor(w2, 32);
        const unsigned int x3 = __shfl_xor(w3, 32);
        const unsigned int x4 = __shfl_xor(w4, 32);
        const unsigned int x5 = __shfl_xor(w5, 32);
        const unsigned int x6 = __shfl_xor(w6, 32);
        const unsigned int x7 = __shfl_xor(w7, 32);
        union { u32x4 u; short8 s8; } pb0, pb1;
        pb0.u = (u32x4){hi ? x2 : w0, hi ? x3 : w1, hi ? w2 : x0, hi ? w3 : x1};
        pb1.u = (u32x4){hi ? x6 : w4, hi ? x7 : w5, hi ? w6 : x4, hi ? w7 : x5};

        // O^T += V^T @ P^T  (col = q, row = d)
        const short8 vf00 = *(const short8*)&Vs[ql][hi * 8];
        const short8 vf01 = *(const short8*)&Vs[ql][16 + hi * 8];
        const short8 vf10 = *(const short8*)&Vs[32 + ql][hi * 8];
        const short8 vf11 = *(const short8*)&Vs[32 + ql][16 + hi * 8];
        o0 = mfma32(vf00, pb0.s8, o0);
        o0 = mfma32(vf01, pb1.s8, o0);
        o1 = mfma32(vf10, pb0.s8, o1);
        o1 = mfma32(vf11, pb1.s8, o1);
    }

    const float linv = 1.0f / l;
    unsigned short* opbase = &OP[((size_t)qg * B_ + b) * E_ + h * D_];
#pragma unroll
    for (int rp = 0; rp < 8; ++rp) {
        const int r0 = rp * 2, r1 = r0 + 1;
        const int d = ((r0 & 3) + 8 * (r0 >> 2)) + 4 * hi;
        *(unsigned int*)(opbase + d) = pack2(o0[r0] * linv, o0[r1] * linv);
        *(unsigned int*)(opbase + 32 + d) = pack2(o1[r0] * linv, o1[r1] * linv);
    }
    if (hi == 0) {
        Mst[(size_t)bh * SQ_ + qg] = m;
        Lst[(size_t)bh * SQ_ + qg] = linv;   // store 1/l
    }
}

// ---------------------------------------------------------------------------
// attn-mean pass, swapped-operand 32x32.
// Block = kv 64 x q 64, ONE 32x32 tile per wave (wave w: kc=w>>1, qc=w&1).
// Small per-head footprint (16KB) keeps L2 reuse alive (round-5 lesson).
// ---------------------------------------------------------------------------
__global__ __launch_bounds__(256, 4)
void attn_probs_kernel(const unsigned short* __restrict__ Qb, const unsigned short* __restrict__ Kb,
                       const float* __restrict__ Mst, const float* __restrict__ Linv,
                       const unsigned char* __restrict__ condm, float* __restrict__ out1) {
    const int kv0 = blockIdx.x * 64;
    const int b = blockIdx.z;
    const int t = threadIdx.x, w = t >> 6, lane = t & 63;
    const int ql = lane & 31, hi = lane >> 5;
    const int kc = w >> 1, qc = w & 1;
    const int qg = blockIdx.y * 64 + qc * 32 + ql;

    __shared__ char smem[17408];                 // Ks (8KB) aliased with Tr (16.9KB)
    unsigned short* Ks = (unsigned short*)smem;  // 64x64 u16 XOR-swizzled
    float* Tr = (float*)smem;                    // 4 waves x 32x33 f32
    __shared__ unsigned int cjw2[2];

    // cj bit words for the block's two 32-k groups (one ballot in wave 0)
    if (t < 64) {
        const int kvv = kv0 + t;
        int pred = 0;
        if (kvv >= 1 && kvv < SKV_) pred = condm[b * SQ_ + kvv - 1];
        const unsigned long long bal = __ballot(pred != 0);
        if (t == 0) { cjw2[0] = (unsigned int)bal; cjw2[1] = (unsigned int)(bal >> 32); }
    }
    const unsigned int ci = condm[b * SQ_ + qg];
    __syncthreads();

    // mask word for this lane's (q, kv-group), pre-shifted by hi*4
    const int kvg = kv0 + kc * 32;
    unsigned int mb;
    {
        const unsigned int cjw = cjw2[kc];
        const int T = qg + 1 - kvg;
        unsigned int causalw;
        if (T < 0) causalw = ~0u;
        else if (T >= 31) causalw = 0u;
        else causalw = (~0u) << (T + 1);
        mb = ci ? ~cjw : causalw;
        if (kvg == 0) mb &= ~1u;                 // text column always visible
    }
    const unsigned int mbs = mb >> (hi * 4);

    const int krow = t >> 2;                     // 0..63
    const int kseg2 = (t & 3) * 2;
    int ksrc = kv0 + krow;
    if (ksrc >= SKVP_) ksrc = SKVP_ - 1;         // clamp into zeroed pad

    float acc[16] = {};

#pragma unroll 1
    for (int h = 0; h < H_; ++h) {
        const int bh = b * H_ + h;
        __syncthreads();
        {
            const unsigned short* kp = &Kb[((size_t)bh * SKVP_ + ksrc) * D_];
            *(short8*)&Ks[krow * 64 + ((kseg2 ^ (krow & 7)) * 8)] = *(const short8*)&kp[kseg2 * 8];
            *(short8*)&Ks[krow * 64 + (((kseg2 + 1) ^ (krow & 7)) * 8)] = *(const short8*)&kp[(kseg2 + 1) * 8];
        }
        __syncthreads();

        const size_t qoff = ((size_t)bh * SQ_ + qg) * D_;
        short8 qf[4];
#pragma unroll
        for (int tt = 0; tt < 4; ++tt) qf[tt] = *(const short8*)&Qb[qoff + tt * 16 + hi * 8];
        const float mh = Mst[(size_t)bh * SQ_ + qg];
        const float li = Linv[(size_t)bh * SQ_ + qg] * (1.0f / 16.0f);

        f32x16 S = {};
#pragma unroll
        for (int tt = 0; tt < 4; ++tt) {
            const short8 kf = *(const short8*)&Ks[(kc * 32 + ql) * 64 + (((2 * tt + hi) ^ (ql & 7)) * 8)];
            S = mfma32(kf, qf[tt], S);
        }
#pragma unroll
        for (int r = 0; r < 16; ++r) {
            const int kk = (r & 3) + 8 * (r >> 2);
            const float p = ((mbs >> kk) & 1u) ? 0.f : __expf(S[r] - mh);
            acc[r] += p * li;
        }
    }

    __syncthreads();   // all waves done with Ks before Tr overwrites it

    // epilogue: per-wave 32x32 transpose via LDS, coalesced stores
    float* Trw = &Tr[w * (32 * 33)];
#pragma unroll
    for (int r = 0; r < 16; ++r) {
        const int kk = (r & 3) + 8 * (r >> 2) + 4 * hi;
        Trw[ql * 33 + kk] = acc[r];
    }
    const int kcol = kv0 + kc * 32 + ql;
    const int qb_w = blockIdx.y * 64 + qc * 32;
    if (kcol < SKV_) {
#pragma unroll
        for (int step = 0; step < 16; ++step) {
            const int q2 = step * 2 + hi;
            out1[((size_t)b * SQ_ + qb_w + q2) * SKV_ + kcol] = Trw[q2 * 33 + ql];
        }
    }
}

// ---------------------------------------------------------------------------
extern "C" void kernel_launch(void* const* d_in, const int* in_sizes, int n_in,
                              void* d_out, int out_size, void* d_ws, size_t ws_size,
                              hipStream_t stream) {
    const float* q   = (const float*)d_in[0];
    const float* kv  = (const float*)d_in[1];
    const void*  msk = d_in[2];
    const float* Wq  = (const float*)d_in[3];
    const float* bq  = (const float*)d_in[4];
    const float* Wk  = (const float*)d_in[5];
    const float* bk  = (const float*)d_in[6];
    const float* Wv  = (const float*)d_in[7];
    const float* bv  = (const float*)d_in[8];
    const float* Wo  = (const float*)d_in[9];
    const float* bo  = (const float*)d_in[10];

    char* ws = (char*)d_ws;
    unsigned short* Qb  = (unsigned short*)(ws);              // 16,777,216 B
    unsigned short* Kb  = (unsigned short*)(ws + 16777216);   // 17,039,360 B
    unsigned short* Vt  = (unsigned short*)(ws + 33816576);   // 17,039,360 B
    unsigned short* OP  = (unsigned short*)(ws + 50855936);   // 16,777,216 B
    float*          Mst = (float*)(ws + 67633152);            //    524,288 B
    float*          Lst = (float*)(ws + 68157440);            //    524,288 B
    unsigned char* condm = (unsigned char*)(ws + 68681728);   //      8,192 B

    float* out0 = (float*)d_out;
    float* out1 = out0 + (size_t)SQ_ * B_ * E_;

    decode_mask_kernel<<<1, 256, 0, stream>>>(msk, condm);
    gemm_kernel<0><<<dim3(128, 16), 256, 0, stream>>>((const void*)q, Wq, bq, (void*)Qb, SQ_ * B_);
    gemm_kernel<1><<<dim3(129, 16), 256, 0, stream>>>((const void*)kv, Wk, bk, (void*)Kb, SKV_ * B_);
    gemm_kernel<2><<<dim3(129, 16), 256, 0, stream>>>((const void*)kv, Wv, bv, (void*)Vt, SKV_ * B_);
    zero_pad_kernel<<<992, 256, 0, stream>>>(Kb, Vt);
    attn_fwd_kernel<<<dim3(16, 16, 4), 256, 0, stream>>>(Qb, Kb, Vt, condm, OP, Mst, Lst);
    attn_probs_kernel<<<dim3(33, 32, 4), 256, 0, stream>>>(Qb, Kb, Mst, Lst, condm, out1);
    gemm_kernel<3><<<dim3(128, 16), 256, 0, stream>>>((const void*)OP, Wo, bo, (void*)out0, SQ_ * B_);
}

// Round 8
// 534.476 us; speedup vs baseline: 1.6462x; 1.1184x over previous
//
#include <hip/hip_runtime.h>
#include <hip/hip_bf16.h>

#define B_ 4
#define H_ 16
#define D_ 64
#define E_ 1024
#define SQ_ 2048
#define SKV_ 2049
#define SKVP_ 2080
#define QSCALE 0.18033688011112042f   /* (1/8) * log2(e) */

typedef __attribute__((ext_vector_type(8))) short short8;
typedef __attribute__((ext_vector_type(4))) float f32x4;
typedef __attribute__((ext_vector_type(16))) float f32x16;
typedef __attribute__((ext_vector_type(4))) unsigned int u32x4;

static __device__ __forceinline__ float ex2(float x) {
    return __builtin_amdgcn_exp2f(x);   // raw v_exp_f32 (2^x)
}

static __device__ __forceinline__ unsigned short f2bf(float f) {
    unsigned int u = __float_as_uint(f);
    u += 0x7FFFu + ((u >> 16) & 1u);
    return (unsigned short)(u >> 16);
}
// HW packed convert: v_cvt_pk_bf16_f32 (RNE), a -> low, b -> high
static __device__ __forceinline__ unsigned int pack2(float a, float b) {
    union { __hip_bfloat162 h; unsigned int u; } cv;
    cv.h = __float22bfloat162_rn(make_float2(a, b));
    return cv.u;
}

static __device__ __forceinline__ f32x4 mfma16(short8 a, short8 b, f32x4 c) {
    return __builtin_amdgcn_mfma_f32_16x16x32_bf16(a, b, c, 0, 0, 0);
}
static __device__ __forceinline__ f32x16 mfma32(short8 a, short8 b, f32x16 c) {
    return __builtin_amdgcn_mfma_f32_32x32x16_bf16(a, b, c, 0, 0, 0);
}

// ---------------------------------------------------------------------------
// Mask decode: sniff dtype (uint8 bool vs int32/f32 0/1 words), write uint8.
// ---------------------------------------------------------------------------
__global__ void decode_mask_kernel(const void* __restrict__ mraw,
                                   unsigned char* __restrict__ condm) {
    __shared__ int flags[2];
    const int t = threadIdx.x;
    if (t < 2) flags[t] = 1;
    __syncthreads();
    const unsigned int* wp = (const unsigned int*)mraw;
    int okI = 1, okF = 1;
    for (int i = t; i < 2048; i += 256) {
        unsigned int w = wp[i];
        if (w > 1u) okI = 0;
        if (w != 0u && w != 0x3F800000u) okF = 0;
    }
    if (!okI) atomicAnd(&flags[0], 0);
    if (!okF) atomicAnd(&flags[1], 0);
    __syncthreads();
    const int isWord = flags[0] | flags[1];
    for (int i = t; i < B_ * SQ_; i += 256) {
        unsigned char v;
        if (isWord) v = (unsigned char)(wp[i] != 0u);
        else        v = (unsigned char)(((const unsigned char*)mraw)[i] != 0);
        condm[i] = v;
    }
}

// ---------------------------------------------------------------------------
// GEMM: C = A @ W^T + bias. MODE 0: Q (scaled by QSCALE, exp2 domain).
// MODE 3: bf16 OP rows -> f32 out.
// ---------------------------------------------------------------------------
template <int MODE>
__global__ __launch_bounds__(256, 3)
void gemm_kernel(const void* __restrict__ Ain, const float* __restrict__ W,
                 const float* __restrict__ bias, void* __restrict__ Outp, int nrows) {
    __shared__ unsigned short As[64][40];
    __shared__ unsigned short Ws[64][40];
    const int t = threadIdx.x;
    const int row0 = blockIdx.x * 64;
    const int col0 = blockIdx.y * 64;
    const int w = t >> 6, lane = t & 63;
    const int wm = w >> 1, wn = w & 1;
    const int lr = lane & 15, lg = lane >> 4, lk = lg * 8;
    const int srow = t >> 2, sk = (t & 3) * 8;
    int arow = row0 + srow;
    if (arow >= nrows) arow = nrows - 1;
    const int wrow = col0 + srow;

    f32x4 acc[2][2] = {};

#pragma unroll 1
    for (int k0 = 0; k0 < E_; k0 += 32) {
        if constexpr (MODE == 3) {
            const unsigned short* A = (const unsigned short*)Ain;
            *(short8*)&As[srow][sk] = *(const short8*)&A[(size_t)arow * E_ + k0 + sk];
        } else {
            const float* A = (const float*)Ain;
            const float* ap = &A[(size_t)arow * E_ + k0 + sk];
            short8 v;
#pragma unroll
            for (int i = 0; i < 8; ++i) v[i] = (short)f2bf(ap[i]);
            *(short8*)&As[srow][sk] = v;
        }
        {
            const float* wpr = &W[(size_t)wrow * E_ + k0 + sk];
            short8 v;
#pragma unroll
            for (int i = 0; i < 8; ++i) v[i] = (short)f2bf(wpr[i]);
            *(short8*)&Ws[srow][sk] = v;
        }
        __syncthreads();
        short8 a0 = *(const short8*)&As[wm * 32 + lr][lk];
        short8 a1 = *(const short8*)&As[wm * 32 + 16 + lr][lk];
        short8 b0 = *(const short8*)&Ws[wn * 32 + lr][lk];
        short8 b1 = *(const short8*)&Ws[wn * 32 + 16 + lr][lk];
        acc[0][0] = mfma16(a0, b0, acc[0][0]);
        acc[0][1] = mfma16(a0, b1, acc[0][1]);
        acc[1][0] = mfma16(a1, b0, acc[1][0]);
        acc[1][1] = mfma16(a1, b1, acc[1][1]);
        __syncthreads();
    }

#pragma unroll
    for (int ni = 0; ni < 2; ++ni) {
        const int c = col0 + wn * 32 + ni * 16 + lr;
        const float bv = bias[c];
#pragma unroll
        for (int mi = 0; mi < 2; ++mi) {
#pragma unroll
            for (int r4 = 0; r4 < 4; ++r4) {
                const int r = row0 + wm * 32 + mi * 16 + lg * 4 + r4;
                if (r >= nrows) continue;
                float v = acc[mi][ni][r4] + bv;
                if constexpr (MODE == 0) {
                    v *= QSCALE;  // fold 1/sqrt(d) * log2(e) into Q (exp2 domain)
                    const int sq = r >> 2, b = r & 3;
                    const int h = c >> 6, d = c & 63;
                    ((unsigned short*)Outp)[(((size_t)(b * H_ + h) * SQ_) + sq) * D_ + d] = f2bf(v);
                } else {
                    ((float*)Outp)[(size_t)r * E_ + c] = v;
                }
            }
        }
    }
}

// ---------------------------------------------------------------------------
// Fused K+V GEMM: stages kv rows once, computes K-tile and V^T-tile.
// ---------------------------------------------------------------------------
__global__ __launch_bounds__(256, 3)
void gemm_kv_kernel(const float* __restrict__ A, const float* __restrict__ Wk,
                    const float* __restrict__ bk, const float* __restrict__ Wv,
                    const float* __restrict__ bv, unsigned short* __restrict__ Kb,
                    unsigned short* __restrict__ Vt, int nrows) {
    __shared__ unsigned short As[64][40];
    __shared__ unsigned short WsK[64][40];
    __shared__ unsigned short WsV[64][40];
    const int t = threadIdx.x;
    const int row0 = blockIdx.x * 64;
    const int col0 = blockIdx.y * 64;
    const int w = t >> 6, lane = t & 63;
    const int wm = w >> 1, wn = w & 1;
    const int lr = lane & 15, lg = lane >> 4, lk = lg * 8;
    const int srow = t >> 2, sk = (t & 3) * 8;
    int arow = row0 + srow;
    if (arow >= nrows) arow = nrows - 1;
    const int wrow = col0 + srow;

    f32x4 accK[2][2] = {};
    f32x4 accV[2][2] = {};

#pragma unroll 1
    for (int k0 = 0; k0 < E_; k0 += 32) {
        {
            const float* ap = &A[(size_t)arow * E_ + k0 + sk];
            short8 v;
#pragma unroll
            for (int i = 0; i < 8; ++i) v[i] = (short)f2bf(ap[i]);
            *(short8*)&As[srow][sk] = v;
        }
        {
            const float* wpr = &Wk[(size_t)wrow * E_ + k0 + sk];
            short8 v;
#pragma unroll
            for (int i = 0; i < 8; ++i) v[i] = (short)f2bf(wpr[i]);
            *(short8*)&WsK[srow][sk] = v;
        }
        {
            const float* wpr = &Wv[(size_t)wrow * E_ + k0 + sk];
            short8 v;
#pragma unroll
            for (int i = 0; i < 8; ++i) v[i] = (short)f2bf(wpr[i]);
            *(short8*)&WsV[srow][sk] = v;
        }
        __syncthreads();
        short8 a0 = *(const short8*)&As[wm * 32 + lr][lk];
        short8 a1 = *(const short8*)&As[wm * 32 + 16 + lr][lk];
        short8 k0f = *(const short8*)&WsK[wn * 32 + lr][lk];
        short8 k1f = *(const short8*)&WsK[wn * 32 + 16 + lr][lk];
        short8 v0f = *(const short8*)&WsV[wn * 32 + lr][lk];
        short8 v1f = *(const short8*)&WsV[wn * 32 + 16 + lr][lk];
        accK[0][0] = mfma16(a0, k0f, accK[0][0]);
        accK[0][1] = mfma16(a0, k1f, accK[0][1]);
        accK[1][0] = mfma16(a1, k0f, accK[1][0]);
        accK[1][1] = mfma16(a1, k1f, accK[1][1]);
        accV[0][0] = mfma16(a0, v0f, accV[0][0]);
        accV[0][1] = mfma16(a0, v1f, accV[0][1]);
        accV[1][0] = mfma16(a1, v0f, accV[1][0]);
        accV[1][1] = mfma16(a1, v1f, accV[1][1]);
        __syncthreads();
    }

#pragma unroll
    for (int ni = 0; ni < 2; ++ni) {
        const int c = col0 + wn * 32 + ni * 16 + lr;
        const float bkc = bk[c];
        const float bvc = bv[c];
        const int h = c >> 6, d = c & 63;
#pragma unroll
        for (int mi = 0; mi < 2; ++mi) {
#pragma unroll
            for (int r4 = 0; r4 < 4; ++r4) {
                const int r = row0 + wm * 32 + mi * 16 + lg * 4 + r4;
                if (r >= nrows) continue;
                const int kvi = r >> 2, b = r & 3;
                Kb[(((size_t)(b * H_ + h) * SKVP_) + kvi) * D_ + d] = f2bf(accK[mi][ni][r4] + bkc);
                Vt[(((size_t)(b * H_ + h) * D_) + d) * SKVP_ + kvi] = f2bf(accV[mi][ni][r4] + bvc);
            }
        }
    }
}

// ---------------------------------------------------------------------------
// Zero the kv padding rows/cols (2049..2079) of K and V^T.
// ---------------------------------------------------------------------------
__global__ void zero_pad_kernel(unsigned short* __restrict__ Kb,
                                unsigned short* __restrict__ Vt) {
    const int idx = blockIdx.x * blockDim.x + threadIdx.x;
    const int NK = 64 * 31 * 64;
    if (idx < NK) {
        const int bh = idx / (31 * 64);
        const int rem = idx - bh * 31 * 64;
        const int kvi = SKV_ + rem / 64;
        const int d = rem & 63;
        Kb[((size_t)bh * SKVP_ + kvi) * D_ + d] = 0;
    } else {
        const int j = idx - NK;
        if (j < 4096 * 31) {
            const int row = j / 31;
            const int kvi = SKV_ + (j - row * 31);
            Vt[(size_t)row * SKVP_ + kvi] = 0;
        }
    }
}

// ---------------------------------------------------------------------------
// Flash attention fwd, swapped-operand 32x32, exp2 domain, KV-tile 64,
// defer-max rescale, HW packed bf16 convert. Stores m(log2) and 1/l.
// ---------------------------------------------------------------------------
__global__ __launch_bounds__(256, 4)
void attn_fwd_kernel(const unsigned short* __restrict__ Qb, const unsigned short* __restrict__ Kb,
                     const unsigned short* __restrict__ Vt, const unsigned char* __restrict__ condm,
                     unsigned short* __restrict__ OP, float* __restrict__ Mst,
                     float* __restrict__ Lst) {
    const int h = blockIdx.y, b = blockIdx.z;
    const int bh = b * H_ + h;
    const int t = threadIdx.x, w = t >> 6, lane = t & 63;
    const int ql = lane & 31;
    const int hi = lane >> 5;
    const int qg = blockIdx.x * 128 + w * 32 + ql;

    __shared__ unsigned short Ks[64 * 64];   // XOR-swizzled, 16B granules
    __shared__ unsigned short Vs[64][72];    // V^T rows (d), 64 kv cols + pad
    __shared__ unsigned int cjb[66];

    for (int g = t; g < 66; g += 256) {
        unsigned int wbits = 0;
        const int base = g * 32;
#pragma unroll 4
        for (int i = 0; i < 32; ++i) {
            const int kv = base + i;
            if (kv >= 1 && kv < SKV_) wbits |= ((unsigned int)condm[b * SQ_ + kv - 1]) << i;
        }
        cjb[g] = wbits;
    }

    const size_t qoff = ((size_t)bh * SQ_ + qg) * D_;
    short8 qf[4];
#pragma unroll
    for (int tt = 0; tt < 4; ++tt) qf[tt] = *(const short8*)&Qb[qoff + tt * 16 + hi * 8];

    const unsigned int ci = condm[b * SQ_ + qg];

    float m = -__builtin_inff(), l = 0.f;
    f32x16 o0 = {}, o1 = {};

    const int krow = t >> 2, kseg2 = (t & 3) * 2;   // K staging: 64 rows x 2 granules
    const int vrow = t >> 2, vc0 = (t & 3) * 16;    // V staging: 64 rows x 2 short8
    const unsigned short* Kbase = &Kb[(size_t)bh * SKVP_ * D_];
    const unsigned short* Vbase = &Vt[(size_t)bh * D_ * SKVP_];

#pragma unroll 1
    for (int kv0 = 0; kv0 < SKVP_; kv0 += 64) {
        __syncthreads();
        {
            int krg = kv0 + krow;
            if (krg > SKVP_ - 1) krg = SKVP_ - 1;            // clamp into zeroed pad
            const unsigned short* kp = &Kbase[(size_t)krg * D_];
            *(short8*)&Ks[krow * 64 + ((kseg2 ^ (krow & 7)) * 8)] = *(const short8*)&kp[kseg2 * 8];
            *(short8*)&Ks[krow * 64 + (((kseg2 + 1) ^ (krow & 7)) * 8)] = *(const short8*)&kp[(kseg2 + 1) * 8];
            int vc = kv0 + vc0;
            if (vc > SKVP_ - 8) vc = SKVP_ - 8;              // clamp (cols >=2049 are zero)
            int vc2 = kv0 + vc0 + 8;
            if (vc2 > SKVP_ - 8) vc2 = SKVP_ - 8;
            const unsigned short* vp = &Vbase[(size_t)vrow * SKVP_];
            *(short8*)&Vs[vrow][vc0] = *(const short8*)&vp[vc];
            *(short8*)&Vs[vrow][vc0 + 8] = *(const short8*)&vp[vc2];
        }
        __syncthreads();

#pragma unroll
        for (int ksub = 0; ksub < 2; ++ksub) {
            const int kvg = kv0 + ksub * 32;
            // S^T = K @ Q^T  (col = q = ql, row = k)
            f32x16 S = {};
#pragma unroll
            for (int tt = 0; tt < 4; ++tt) {
                const short8 kf = *(const short8*)&Ks[(ksub * 32 + ql) * 64 + (((2 * tt + hi) ^ (ql & 7)) * 8)];
                S = mfma32(kf, qf[tt], S);
            }

            // mask bits: bit i => kvg+i masked for this q-row
            const unsigned int cjw = cjb[kvg >> 5];
            const int T = qg + 1 - kvg;
            unsigned int causalw;
            if (T < 0) causalw = ~0u;
            else if (T >= 31) causalw = 0u;
            else causalw = (~0u) << (T + 1);
            unsigned int mb = ci ? ~cjw : causalw;
            if (kvg == 0) mb &= ~1u;     // text column always visible
            const unsigned int mbs = mb >> (hi * 4);

#pragma unroll
            for (int r = 0; r < 16; ++r) {
                const int kc = (r & 3) + 8 * (r >> 2);
                S[r] = ((mbs >> kc) & 1u) ? -__builtin_inff() : S[r];
            }
            // max tree (max3-fusable triples)
            float t0 = fmaxf(fmaxf(S[0], S[1]), S[2]);
            float t1 = fmaxf(fmaxf(S[3], S[4]), S[5]);
            float t2 = fmaxf(fmaxf(S[6], S[7]), S[8]);
            float t3 = fmaxf(fmaxf(S[9], S[10]), S[11]);
            float t4 = fmaxf(fmaxf(S[12], S[13]), S[14]);
            float rmax = fmaxf(fmaxf(fmaxf(t0, t1), t2), fmaxf(fmaxf(t3, t4), S[15]));
            rmax = fmaxf(rmax, __shfl_xor(rmax, 32));

            // defer-max: only rescale when max grew by > 8 (log2 domain)
            if (!__all(rmax <= m + 8.0f)) {
                const float mn = fmaxf(m, rmax);
                const float alpha = ex2(m - mn);
                l *= alpha;
                o0 *= alpha;
                o1 *= alpha;
                m = mn;
            }

#pragma unroll
            for (int r = 0; r < 16; ++r) S[r] = ex2(S[r] - m);   // exp2(-inf)=0
            const float a0s = (S[0] + S[1]) + (S[2] + S[3]);
            const float a1s = (S[4] + S[5]) + (S[6] + S[7]);
            const float a2s = (S[8] + S[9]) + (S[10] + S[11]);
            const float a3s = (S[12] + S[13]) + (S[14] + S[15]);
            float psum = (a0s + a1s) + (a2s + a3s);
            psum += __shfl_xor(psum, 32);
            l += psum;

            // pack P pairs to bf16 words (HW cvt_pk), exchange halves
            const unsigned int w0 = pack2(S[0], S[1]);
            const unsigned int w1 = pack2(S[2], S[3]);
            const unsigned int w2 = pack2(S[4], S[5]);
            const unsigned int w3 = pack2(S[6], S[7]);
            const unsigned int w4 = pack2(S[8], S[9]);
            const unsigned int w5 = pack2(S[10], S[11]);
            const unsigned int w6 = pack2(S[12], S[13]);
            const unsigned int w7 = pack2(S[14], S[15]);
            const unsigned int x0 = __shfl_xor(w0, 32);
            const unsigned int x1 = __shfl_xor(w1, 32);
            const unsigned int x2 = __shfl_xor(w2, 32);
            const unsigned int x3 = __shfl_xor(w3, 32);
            const unsigned int x4 = __shfl_xor(w4, 32);
            const unsigned int x5 = __shfl_xor(w5, 32);
            const unsigned int x6 = __shfl_xor(w6, 32);
            const unsigned int x7 = __shfl_xor(w7, 32);
            union { u32x4 u; short8 s8; } pb0, pb1;
            pb0.u = (u32x4){hi ? x2 : w0, hi ? x3 : w1, hi ? w2 : x0, hi ? w3 : x1};
            pb1.u = (u32x4){hi ? x6 : w4, hi ? x7 : w5, hi ? w6 : x4, hi ? w7 : x5};

            // O^T += V^T @ P^T  (col = q, row = d)
            const short8 vf00 = *(const short8*)&Vs[ql][ksub * 32 + hi * 8];
            const short8 vf01 = *(const short8*)&Vs[ql][ksub * 32 + 16 + hi * 8];
            const short8 vf10 = *(const short8*)&Vs[32 + ql][ksub * 32 + hi * 8];
            const short8 vf11 = *(const short8*)&Vs[32 + ql][ksub * 32 + 16 + hi * 8];
            o0 = mfma32(vf00, pb0.s8, o0);
            o0 = mfma32(vf01, pb1.s8, o0);
            o1 = mfma32(vf10, pb0.s8, o1);
            o1 = mfma32(vf11, pb1.s8, o1);
        }
    }

    const float linv = 1.0f / l;
    unsigned short* opbase = &OP[((size_t)qg * B_ + b) * E_ + h * D_];
#pragma unroll
    for (int rp = 0; rp < 8; ++rp) {
        const int r0 = rp * 2, r1 = r0 + 1;
        const int d = ((r0 & 3) + 8 * (r0 >> 2)) + 4 * hi;
        *(unsigned int*)(opbase + d) = pack2(o0[r0] * linv, o0[r1] * linv);
        *(unsigned int*)(opbase + 32 + d) = pack2(o1[r0] * linv, o1[r1] * linv);
    }
    if (hi == 0) {
        Mst[(size_t)bh * SQ_ + qg] = m;        // log2 domain
        Lst[(size_t)bh * SQ_ + qg] = linv;     // 1/l
    }
}

// ---------------------------------------------------------------------------
// attn-mean pass, swapped-operand 32x32 (exp2 domain).
// Block = kv 64 x q 64, ONE 32x32 tile per wave (wave w: kc=w>>1, qc=w&1).
// ---------------------------------------------------------------------------
__global__ __launch_bounds__(256, 4)
void attn_probs_kernel(const unsigned short* __restrict__ Qb, const unsigned short* __restrict__ Kb,
                       const float* __restrict__ Mst, const float* __restrict__ Linv,
                       const unsigned char* __restrict__ condm, float* __restrict__ out1) {
    const int kv0 = blockIdx.x * 64;
    const int b = blockIdx.z;
    const int t = threadIdx.x, w = t >> 6, lane = t & 63;
    const int ql = lane & 31, hi = lane >> 5;
    const int kc = w >> 1, qc = w & 1;
    const int qg = blockIdx.y * 64 + qc * 32 + ql;

    __shared__ char smem[17408];                 // Ks (8KB) aliased with Tr (16.9KB)
    unsigned short* Ks = (unsigned short*)smem;  // 64x64 u16 XOR-swizzled
    float* Tr = (float*)smem;                    // 4 waves x 32x33 f32
    __shared__ unsigned int cjw2[2];

    if (t < 64) {
        const int kvv = kv0 + t;
        int pred = 0;
        if (kvv >= 1 && kvv < SKV_) pred = condm[b * SQ_ + kvv - 1];
        const unsigned long long bal = __ballot(pred != 0);
        if (t == 0) { cjw2[0] = (unsigned int)bal; cjw2[1] = (unsigned int)(bal >> 32); }
    }
    const unsigned int ci = condm[b * SQ_ + qg];
    __syncthreads();

    const int kvg = kv0 + kc * 32;
    unsigned int mb;
    {
        const unsigned int cjw = cjw2[kc];
        const int T = qg + 1 - kvg;
        unsigned int causalw;
        if (T < 0) causalw = ~0u;
        else if (T >= 31) causalw = 0u;
        else causalw = (~0u) << (T + 1);
        mb = ci ? ~cjw : causalw;
        if (kvg == 0) mb &= ~1u;                 // text column always visible
    }
    const unsigned int mbs = mb >> (hi * 4);

    const int krow = t >> 2;
    const int kseg2 = (t & 3) * 2;
    int ksrc = kv0 + krow;
    if (ksrc >= SKVP_) ksrc = SKVP_ - 1;         // clamp into zeroed pad

    float acc[16] = {};

#pragma unroll 1
    for (int h = 0; h < H_; ++h) {
        const int bh = b * H_ + h;
        __syncthreads();
        {
            const unsigned short* kp = &Kb[((size_t)bh * SKVP_ + ksrc) * D_];
            *(short8*)&Ks[krow * 64 + ((kseg2 ^ (krow & 7)) * 8)] = *(const short8*)&kp[kseg2 * 8];
            *(short8*)&Ks[krow * 64 + (((kseg2 + 1) ^ (krow & 7)) * 8)] = *(const short8*)&kp[(kseg2 + 1) * 8];
        }
        __syncthreads();

        const size_t qoff = ((size_t)bh * SQ_ + qg) * D_;
        short8 qf[4];
#pragma unroll
        for (int tt = 0; tt < 4; ++tt) qf[tt] = *(const short8*)&Qb[qoff + tt * 16 + hi * 8];
        const float mh = Mst[(size_t)bh * SQ_ + qg];
        const float li = Linv[(size_t)bh * SQ_ + qg] * (1.0f / 16.0f);

        f32x16 S = {};
#pragma unroll
        for (int tt = 0; tt < 4; ++tt) {
            const short8 kf = *(const short8*)&Ks[(kc * 32 + ql) * 64 + (((2 * tt + hi) ^ (ql & 7)) * 8)];
            S = mfma32(kf, qf[tt], S);
        }
#pragma unroll
        for (int r = 0; r < 16; ++r) {
            const int kk = (r & 3) + 8 * (r >> 2);
            const float p = ((mbs >> kk) & 1u) ? 0.f : ex2(S[r] - mh);
            acc[r] += p * li;
        }
    }

    __syncthreads();   // all waves done with Ks before Tr overwrites it

    float* Trw = &Tr[w * (32 * 33)];
#pragma unroll
    for (int r = 0; r < 16; ++r) {
        const int kk = (r & 3) + 8 * (r >> 2) + 4 * hi;
        Trw[ql * 33 + kk] = acc[r];
    }
    const int kcol = kv0 + kc * 32 + ql;
    const int qb_w = blockIdx.y * 64 + qc * 32;
    if (kcol < SKV_) {
#pragma unroll
        for (int step = 0; step < 16; ++step) {
            const int q2 = step * 2 + hi;
            out1[((size_t)b * SQ_ + qb_w + q2) * SKV_ + kcol] = Trw[q2 * 33 + ql];
        }
    }
}

// ---------------------------------------------------------------------------
extern "C" void kernel_launch(void* const* d_in, const int* in_sizes, int n_in,
                              void* d_out, int out_size, void* d_ws, size_t ws_size,
                              hipStream_t stream) {
    const float* q   = (const float*)d_in[0];
    const float* kv  = (const float*)d_in[1];
    const void*  msk = d_in[2];
    const float* Wq  = (const float*)d_in[3];
    const float* bq  = (const float*)d_in[4];
    const float* Wk  = (const float*)d_in[5];
    const float* bk  = (const float*)d_in[6];
    const float* Wv  = (const float*)d_in[7];
    const float* bv  = (const float*)d_in[8];
    const float* Wo  = (const float*)d_in[9];
    const float* bo  = (const float*)d_in[10];

    char* ws = (char*)d_ws;
    unsigned short* Qb  = (unsigned short*)(ws);              // 16,777,216 B
    unsigned short* Kb  = (unsigned short*)(ws + 16777216);   // 17,039,360 B
    unsigned short* Vt  = (unsigned short*)(ws + 33816576);   // 17,039,360 B
    unsigned short* OP  = (unsigned short*)(ws + 50855936);   // 16,777,216 B
    float*          Mst = (float*)(ws + 67633152);            //    524,288 B
    float*          Lst = (float*)(ws + 68157440);            //    524,288 B
    unsigned char* condm = (unsigned char*)(ws + 68681728);   //      8,192 B

    float* out0 = (float*)d_out;
    float* out1 = out0 + (size_t)SQ_ * B_ * E_;

    decode_mask_kernel<<<1, 256, 0, stream>>>(msk, condm);
    gemm_kernel<0><<<dim3(128, 16), 256, 0, stream>>>((const void*)q, Wq, bq, (void*)Qb, SQ_ * B_);
    gemm_kv_kernel<<<dim3(129, 16), 256, 0, stream>>>(kv, Wk, bk, Wv, bv, Kb, Vt, SKV_ * B_);
    zero_pad_kernel<<<992, 256, 0, stream>>>(Kb, Vt);
    attn_fwd_kernel<<<dim3(16, 16, 4), 256, 0, stream>>>(Qb, Kb, Vt, condm, OP, Mst, Lst);
    attn_probs_kernel<<<dim3(33, 32, 4), 256, 0, stream>>>(Qb, Kb, Mst, Lst, condm, out1);
    gemm_kernel<3><<<dim3(128, 16), 256, 0, stream>>>((const void*)OP, Wo, bo, (void*)out0, SQ_ * B_);
}

// Round 10
// 517.467 us; speedup vs baseline: 1.7003x; 1.0329x over previous
//
#include <hip/hip_runtime.h>
#include <hip/hip_bf16.h>

#define B_ 4
#define H_ 16
#define D_ 64
#define E_ 1024
#define SQ_ 2048
#define SKV_ 2049
#define SKVP_ 2080
#define QSCALE 0.18033688011112042f   /* (1/8) * log2(e) */

typedef __attribute__((ext_vector_type(8))) short short8;
typedef __attribute__((ext_vector_type(4))) float f32x4;
typedef __attribute__((ext_vector_type(16))) float f32x16;
typedef __attribute__((ext_vector_type(4))) unsigned int u32x4;
typedef __attribute__((ext_vector_type(4))) float float4v;

static __device__ __forceinline__ float ex2(float x) {
    return __builtin_amdgcn_exp2f(x);   // raw v_exp_f32 (2^x)
}

static __device__ __forceinline__ unsigned short f2bf(float f) {
    unsigned int u = __float_as_uint(f);
    u += 0x7FFFu + ((u >> 16) & 1u);
    return (unsigned short)(u >> 16);
}
// HW packed convert: v_cvt_pk_bf16_f32 (RNE), a -> low, b -> high
static __device__ __forceinline__ unsigned int pack2(float a, float b) {
    union { __hip_bfloat162 h; unsigned int u; } cv;
    cv.h = __float22bfloat162_rn(make_float2(a, b));
    return cv.u;
}

static __device__ __forceinline__ f32x4 mfma16(short8 a, short8 b, f32x4 c) {
    return __builtin_amdgcn_mfma_f32_16x16x32_bf16(a, b, c, 0, 0, 0);
}
static __device__ __forceinline__ f32x16 mfma32(short8 a, short8 b, f32x16 c) {
    return __builtin_amdgcn_mfma_f32_32x32x16_bf16(a, b, c, 0, 0, 0);
}

// ---------------------------------------------------------------------------
// f32 -> bf16 bulk convert (8 elems/thread/iter, grid-stride)
// ---------------------------------------------------------------------------
__global__ void cvt_bf16_kernel(const float* __restrict__ in,
                                unsigned short* __restrict__ out, int n8) {
    for (int i = blockIdx.x * blockDim.x + threadIdx.x; i < n8; i += gridDim.x * blockDim.x) {
        const float4v a = *(const float4v*)&in[(size_t)i * 8];
        const float4v b = *(const float4v*)&in[(size_t)i * 8 + 4];
        u32x4 o;
        o[0] = pack2(a[0], a[1]);
        o[1] = pack2(a[2], a[3]);
        o[2] = pack2(b[0], b[1]);
        o[3] = pack2(b[2], b[3]);
        *(u32x4*)&out[(size_t)i * 8] = o;
    }
}

// ---------------------------------------------------------------------------
// Mask decode: sniff dtype (uint8 bool vs int32/f32 0/1 words), write uint8.
// ---------------------------------------------------------------------------
__global__ void decode_mask_kernel(const void* __restrict__ mraw,
                                   unsigned char* __restrict__ condm) {
    __shared__ int flags[2];
    const int t = threadIdx.x;
    if (t < 2) flags[t] = 1;
    __syncthreads();
    const unsigned int* wp = (const unsigned int*)mraw;
    int okI = 1, okF = 1;
    for (int i = t; i < 2048; i += 256) {
        unsigned int w = wp[i];
        if (w > 1u) okI = 0;
        if (w != 0u && w != 0x3F800000u) okF = 0;
    }
    if (!okI) atomicAnd(&flags[0], 0);
    if (!okF) atomicAnd(&flags[1], 0);
    __syncthreads();
    const int isWord = flags[0] | flags[1];
    for (int i = t; i < B_ * SQ_; i += 256) {
        unsigned char v;
        if (isWord) v = (unsigned char)(wp[i] != 0u);
        else        v = (unsigned char)(((const unsigned char*)mraw)[i] != 0);
        condm[i] = v;
    }
}

// ---------------------------------------------------------------------------
// 128x128-tile GEMM: C = A @ W^T + bias, A and W pre-converted bf16.
// 4 waves (2x2), each 64x64 via 4x4 16x16x32 frags. 1-D grid with chunked
// XCD swizzle: xcd = bid&7 owns row-blocks rb = rchunk*8+xcd across all cols.
// MODE 0: Q out (x QSCALE), 1: K out, 2: V^T out, 3: f32 out rows (sq,b).
// ---------------------------------------------------------------------------
template <int MODE>
__global__ __launch_bounds__(256, 2)
void gemm128_kernel(const unsigned short* __restrict__ Abf,
                    const unsigned short* __restrict__ Wbf,
                    const float* __restrict__ bias, void* __restrict__ Outp,
                    int nrows, int nrb) {
    const int bid = blockIdx.x;
    const int xcd = bid & 7;
    const int pos = bid >> 3;
    const int cb = pos & 7;
    const int rb = (pos >> 3) * 8 + xcd;
    if (rb >= nrb) return;
    const int row0 = rb * 128, col0 = cb * 128;

    __shared__ unsigned short As[128][40];
    __shared__ unsigned short Ws[128][40];
    const int t = threadIdx.x;
    const int w = t >> 6, lane = t & 63;
    const int wm = w >> 1, wn = w & 1;
    const int lr = lane & 15, lg = lane >> 4, lk = lg * 8;
    const int srow = t >> 1, sc0 = (t & 1) * 16;
    int ar = row0 + srow;
    if (ar >= nrows) ar = nrows - 1;
    const int wrow = col0 + srow;

    f32x4 acc[4][4] = {};

#pragma unroll 1
    for (int k0 = 0; k0 < E_; k0 += 32) {
        {
            const unsigned short* ap = &Abf[(size_t)ar * E_ + k0 + sc0];
            *(short8*)&As[srow][sc0] = *(const short8*)&ap[0];
            *(short8*)&As[srow][sc0 + 8] = *(const short8*)&ap[8];
        }
        {
            const unsigned short* wp2 = &Wbf[(size_t)wrow * E_ + k0 + sc0];
            *(short8*)&Ws[srow][sc0] = *(const short8*)&wp2[0];
            *(short8*)&Ws[srow][sc0 + 8] = *(const short8*)&wp2[8];
        }
        __syncthreads();
        short8 af[4], bf[4];
#pragma unroll
        for (int mi = 0; mi < 4; ++mi) af[mi] = *(const short8*)&As[wm * 64 + mi * 16 + lr][lk];
#pragma unroll
        for (int ni = 0; ni < 4; ++ni) bf[ni] = *(const short8*)&Ws[wn * 64 + ni * 16 + lr][lk];
#pragma unroll
        for (int mi = 0; mi < 4; ++mi)
#pragma unroll
            for (int ni = 0; ni < 4; ++ni)
                acc[mi][ni] = mfma16(af[mi], bf[ni], acc[mi][ni]);
        __syncthreads();
    }

#pragma unroll
    for (int ni = 0; ni < 4; ++ni) {
        const int c = col0 + wn * 64 + ni * 16 + lr;
        const float bv = bias[c];
        const int h = c >> 6, d = c & 63;
#pragma unroll
        for (int mi = 0; mi < 4; ++mi) {
#pragma unroll
            for (int r4 = 0; r4 < 4; ++r4) {
                const int r = row0 + wm * 64 + mi * 16 + lg * 4 + r4;
                if (r >= nrows) continue;
                float v = acc[mi][ni][r4] + bv;
                if constexpr (MODE == 0) {
                    v *= QSCALE;
                    const int sq = r >> 2, b = r & 3;
                    ((unsigned short*)Outp)[(((size_t)(b * H_ + h) * SQ_) + sq) * D_ + d] = f2bf(v);
                } else if constexpr (MODE == 1) {
                    const int kvi = r >> 2, b = r & 3;
                    ((unsigned short*)Outp)[(((size_t)(b * H_ + h) * SKVP_) + kvi) * D_ + d] = f2bf(v);
                } else if constexpr (MODE == 2) {
                    const int kvi = r >> 2, b = r & 3;
                    ((unsigned short*)Outp)[(((size_t)(b * H_ + h) * D_) + d) * SKVP_ + kvi] = f2bf(v);
                } else {
                    ((float*)Outp)[(size_t)r * E_ + c] = v;
                }
            }
        }
    }
}

// ---------------------------------------------------------------------------
// Zero the kv padding rows/cols (2049..2079) of K and V^T.
// ---------------------------------------------------------------------------
__global__ void zero_pad_kernel(unsigned short* __restrict__ Kb,
                                unsigned short* __restrict__ Vt) {
    const int idx = blockIdx.x * blockDim.x + threadIdx.x;
    const int NK = 64 * 31 * 64;
    if (idx < NK) {
        const int bh = idx / (31 * 64);
        const int rem = idx - bh * 31 * 64;
        const int kvi = SKV_ + rem / 64;
        const int d = rem & 63;
        Kb[((size_t)bh * SKVP_ + kvi) * D_ + d] = 0;
    } else {
        const int j = idx - NK;
        if (j < 4096 * 31) {
            const int row = j / 31;
            const int kvi = SKV_ + (j - row * 31);
            Vt[(size_t)row * SKVP_ + kvi] = 0;
        }
    }
}

// ---------------------------------------------------------------------------
// Flash attention fwd, swapped-operand 32x32, exp2 domain, KV-tile 64,
// defer-max rescale, HW packed bf16 convert. Stores m(log2) and 1/l.
// ---------------------------------------------------------------------------
__global__ __launch_bounds__(256, 4)
void attn_fwd_kernel(const unsigned short* __restrict__ Qb, const unsigned short* __restrict__ Kb,
                     const unsigned short* __restrict__ Vt, const unsigned char* __restrict__ condm,
                     unsigned short* __restrict__ OP, float* __restrict__ Mst,
                     float* __restrict__ Lst) {
    const int h = blockIdx.y, b = blockIdx.z;
    const int bh = b * H_ + h;
    const int t = threadIdx.x, w = t >> 6, lane = t & 63;
    const int ql = lane & 31;
    const int hi = lane >> 5;
    const int qg = blockIdx.x * 128 + w * 32 + ql;

    __shared__ unsigned short Ks[64 * 64];   // XOR-swizzled, 16B granules
    __shared__ unsigned short Vs[64][72];    // V^T rows (d), 64 kv cols + pad
    __shared__ unsigned int cjb[66];

    for (int g = t; g < 66; g += 256) {
        unsigned int wbits = 0;
        const int base = g * 32;
#pragma unroll 4
        for (int i = 0; i < 32; ++i) {
            const int kv = base + i;
            if (kv >= 1 && kv < SKV_) wbits |= ((unsigned int)condm[b * SQ_ + kv - 1]) << i;
        }
        cjb[g] = wbits;
    }

    const size_t qoff = ((size_t)bh * SQ_ + qg) * D_;
    short8 qf[4];
#pragma unroll
    for (int tt = 0; tt < 4; ++tt) qf[tt] = *(const short8*)&Qb[qoff + tt * 16 + hi * 8];

    const unsigned int ci = condm[b * SQ_ + qg];

    float m = -__builtin_inff(), l = 0.f;
    f32x16 o0 = {}, o1 = {};

    const int krow = t >> 2, kseg2 = (t & 3) * 2;   // K staging: 64 rows x 2 granules
    const int vrow = t >> 2, vc0 = (t & 3) * 16;    // V staging: 64 rows x 2 short8
    const unsigned short* Kbase = &Kb[(size_t)bh * SKVP_ * D_];
    const unsigned short* Vbase = &Vt[(size_t)bh * D_ * SKVP_];

#pragma unroll 1
    for (int kv0 = 0; kv0 < SKVP_; kv0 += 64) {
        __syncthreads();
        {
            int krg = kv0 + krow;
            if (krg > SKVP_ - 1) krg = SKVP_ - 1;            // clamp into zeroed pad
            const unsigned short* kp = &Kbase[(size_t)krg * D_];
            *(short8*)&Ks[krow * 64 + ((kseg2 ^ (krow & 7)) * 8)] = *(const short8*)&kp[kseg2 * 8];
            *(short8*)&Ks[krow * 64 + (((kseg2 + 1) ^ (krow & 7)) * 8)] = *(const short8*)&kp[(kseg2 + 1) * 8];
            int vc = kv0 + vc0;
            if (vc > SKVP_ - 8) vc = SKVP_ - 8;              // clamp (cols >=2049 are zero)
            int vc2 = kv0 + vc0 + 8;
            if (vc2 > SKVP_ - 8) vc2 = SKVP_ - 8;
            const unsigned short* vp = &Vbase[(size_t)vrow * SKVP_];
            *(short8*)&Vs[vrow][vc0] = *(const short8*)&vp[vc];
            *(short8*)&Vs[vrow][vc0 + 8] = *(const short8*)&vp[vc2];
        }
        __syncthreads();

#pragma unroll
        for (int ksub = 0; ksub < 2; ++ksub) {
            const int kvg = kv0 + ksub * 32;
            // S^T = K @ Q^T  (col = q = ql, row = k)
            f32x16 S = {};
#pragma unroll
            for (int tt = 0; tt < 4; ++tt) {
                const short8 kf = *(const short8*)&Ks[(ksub * 32 + ql) * 64 + (((2 * tt + hi) ^ (ql & 7)) * 8)];
                S = mfma32(kf, qf[tt], S);
            }

            // mask bits: bit i => kvg+i masked for this q-row
            const unsigned int cjw = cjb[kvg >> 5];
            const int T = qg + 1 - kvg;
            unsigned int causalw;
            if (T < 0) causalw = ~0u;
            else if (T >= 31) causalw = 0u;
            else causalw = (~0u) << (T + 1);
            unsigned int mb = ci ? ~cjw : causalw;
            if (kvg == 0) mb &= ~1u;     // text column always visible
            const unsigned int mbs = mb >> (hi * 4);

#pragma unroll
            for (int r = 0; r < 16; ++r) {
                const int kc = (r & 3) + 8 * (r >> 2);
                S[r] = ((mbs >> kc) & 1u) ? -__builtin_inff() : S[r];
            }
            // max tree (max3-fusable triples)
            float t0 = fmaxf(fmaxf(S[0], S[1]), S[2]);
            float t1 = fmaxf(fmaxf(S[3], S[4]), S[5]);
            float t2 = fmaxf(fmaxf(S[6], S[7]), S[8]);
            float t3 = fmaxf(fmaxf(S[9], S[10]), S[11]);
            float t4 = fmaxf(fmaxf(S[12], S[13]), S[14]);
            float rmax = fmaxf(fmaxf(fmaxf(t0, t1), t2), fmaxf(fmaxf(t3, t4), S[15]));
            rmax = fmaxf(rmax, __shfl_xor(rmax, 32));

            // defer-max: only rescale when max grew by > 8 (log2 domain)
            if (!__all(rmax <= m + 8.0f)) {
                const float mn = fmaxf(m, rmax);
                const float alpha = ex2(m - mn);
                l *= alpha;
                o0 *= alpha;
                o1 *= alpha;
                m = mn;
            }

#pragma unroll
            for (int r = 0; r < 16; ++r) S[r] = ex2(S[r] - m);   // exp2(-inf)=0
            const float a0s = (S[0] + S[1]) + (S[2] + S[3]);
            const float a1s = (S[4] + S[5]) + (S[6] + S[7]);
            const float a2s = (S[8] + S[9]) + (S[10] + S[11]);
            const float a3s = (S[12] + S[13]) + (S[14] + S[15]);
            float psum = (a0s + a1s) + (a2s + a3s);
            psum += __shfl_xor(psum, 32);
            l += psum;

            // pack P pairs to bf16 words (HW cvt_pk), exchange halves
            const unsigned int w0 = pack2(S[0], S[1]);
            const unsigned int w1 = pack2(S[2], S[3]);
            const unsigned int w2 = pack2(S[4], S[5]);
            const unsigned int w3 = pack2(S[6], S[7]);
            const unsigned int w4 = pack2(S[8], S[9]);
            const unsigned int w5 = pack2(S[10], S[11]);
            const unsigned int w6 = pack2(S[12], S[13]);
            const unsigned int w7 = pack2(S[14], S[15]);
            const unsigned int x0 = __shfl_xor(w0, 32);
            const unsigned int x1 = __shfl_xor(w1, 32);
            const unsigned int x2 = __shfl_xor(w2, 32);
            const unsigned int x3 = __shfl_xor(w3, 32);
            const unsigned int x4 = __shfl_xor(w4, 32);
            const unsigned int x5 = __shfl_xor(w5, 32);
            const unsigned int x6 = __shfl_xor(w6, 32);
            const unsigned int x7 = __shfl_xor(w7, 32);
            union { u32x4 u; short8 s8; } pb0, pb1;
            pb0.u = (u32x4){hi ? x2 : w0, hi ? x3 : w1, hi ? w2 : x0, hi ? w3 : x1};
            pb1.u = (u32x4){hi ? x6 : w4, hi ? x7 : w5, hi ? w6 : x4, hi ? w7 : x5};

            // O^T += V^T @ P^T  (col = q, row = d)
            const short8 vf00 = *(const short8*)&Vs[ql][ksub * 32 + hi * 8];
            const short8 vf01 = *(const short8*)&Vs[ql][ksub * 32 + 16 + hi * 8];
            const short8 vf10 = *(const short8*)&Vs[32 + ql][ksub * 32 + hi * 8];
            const short8 vf11 = *(const short8*)&Vs[32 + ql][ksub * 32 + 16 + hi * 8];
            o0 = mfma32(vf00, pb0.s8, o0);
            o0 = mfma32(vf01, pb1.s8, o0);
            o1 = mfma32(vf10, pb0.s8, o1);
            o1 = mfma32(vf11, pb1.s8, o1);
        }
    }

    const float linv = 1.0f / l;
    unsigned short* opbase = &OP[((size_t)qg * B_ + b) * E_ + h * D_];
#pragma unroll
    for (int rp = 0; rp < 8; ++rp) {
        const int r0 = rp * 2, r1 = r0 + 1;
        const int d = ((r0 & 3) + 8 * (r0 >> 2)) + 4 * hi;
        *(unsigned int*)(opbase + d) = pack2(o0[r0] * linv, o0[r1] * linv);
        *(unsigned int*)(opbase + 32 + d) = pack2(o1[r0] * linv, o1[r1] * linv);
    }
    if (hi == 0) {
        Mst[(size_t)bh * SQ_ + qg] = m;        // log2 domain
        Lst[(size_t)bh * SQ_ + qg] = linv;     // 1/l
    }
}

// ---------------------------------------------------------------------------
// attn-mean pass, swapped-operand 32x32 (exp2 domain).
// Block = kv 64 x q 64, ONE 32x32 tile per wave (wave w: kc=w>>1, qc=w&1).
// ---------------------------------------------------------------------------
__global__ __launch_bounds__(256, 4)
void attn_probs_kernel(const unsigned short* __restrict__ Qb, const unsigned short* __restrict__ Kb,
                       const float* __restrict__ Mst, const float* __restrict__ Linv,
                       const unsigned char* __restrict__ condm, float* __restrict__ out1) {
    const int kv0 = blockIdx.x * 64;
    const int b = blockIdx.z;
    const int t = threadIdx.x, w = t >> 6, lane = t & 63;
    const int ql = lane & 31, hi = lane >> 5;
    const int kc = w >> 1, qc = w & 1;
    const int qg = blockIdx.y * 64 + qc * 32 + ql;

    __shared__ char smem[17408];                 // Ks (8KB) aliased with Tr (16.9KB)
    unsigned short* Ks = (unsigned short*)smem;  // 64x64 u16 XOR-swizzled
    float* Tr = (float*)smem;                    // 4 waves x 32x33 f32
    __shared__ unsigned int cjw2[2];

    if (t < 64) {
        const int kvv = kv0 + t;
        int pred = 0;
        if (kvv >= 1 && kvv < SKV_) pred = condm[b * SQ_ + kvv - 1];
        const unsigned long long bal = __ballot(pred != 0);
        if (t == 0) { cjw2[0] = (unsigned int)bal; cjw2[1] = (unsigned int)(bal >> 32); }
    }
    const unsigned int ci = condm[b * SQ_ + qg];
    __syncthreads();

    const int kvg = kv0 + kc * 32;
    unsigned int mb;
    {
        const unsigned int cjw = cjw2[kc];
        const int T = qg + 1 - kvg;
        unsigned int causalw;
        if (T < 0) causalw = ~0u;
        else if (T >= 31) causalw = 0u;
        else causalw = (~0u) << (T + 1);
        mb = ci ? ~cjw : causalw;
        if (kvg == 0) mb &= ~1u;                 // text column always visible
    }
    const unsigned int mbs = mb >> (hi * 4);

    const int krow = t >> 2;
    const int kseg2 = (t & 3) * 2;
    int ksrc = kv0 + krow;
    if (ksrc >= SKVP_) ksrc = SKVP_ - 1;         // clamp into zeroed pad

    float acc[16] = {};

#pragma unroll 1
    for (int h = 0; h < H_; ++h) {
        const int bh = b * H_ + h;
        __syncthreads();
        {
            const unsigned short* kp = &Kb[((size_t)bh * SKVP_ + ksrc) * D_];
            *(short8*)&Ks[krow * 64 + ((kseg2 ^ (krow & 7)) * 8)] = *(const short8*)&kp[kseg2 * 8];
            *(short8*)&Ks[krow * 64 + (((kseg2 + 1) ^ (krow & 7)) * 8)] = *(const short8*)&kp[(kseg2 + 1) * 8];
        }
        __syncthreads();

        const size_t qoff = ((size_t)bh * SQ_ + qg) * D_;
        short8 qf[4];
#pragma unroll
        for (int tt = 0; tt < 4; ++tt) qf[tt] = *(const short8*)&Qb[qoff + tt * 16 + hi * 8];
        const float mh = Mst[(size_t)bh * SQ_ + qg];
        const float li = Linv[(size_t)bh * SQ_ + qg] * (1.0f / 16.0f);

        f32x16 S = {};
#pragma unroll
        for (int tt = 0; tt < 4; ++tt) {
            const short8 kf = *(const short8*)&Ks[(kc * 32 + ql) * 64 + (((2 * tt + hi) ^ (ql & 7)) * 8)];
            S = mfma32(kf, qf[tt], S);
        }
#pragma unroll
        for (int r = 0; r < 16; ++r) {
            const int kk = (r & 3) + 8 * (r >> 2);
            const float p = ((mbs >> kk) & 1u) ? 0.f : ex2(S[r] - mh);
            acc[r] += p * li;
        }
    }

    __syncthreads();   // all waves done with Ks before Tr overwrites it

    float* Trw = &Tr[w * (32 * 33)];
#pragma unroll
    for (int r = 0; r < 16; ++r) {
        const int kk = (r & 3) + 8 * (r >> 2) + 4 * hi;
        Trw[ql * 33 + kk] = acc[r];
    }
    const int kcol = kv0 + kc * 32 + ql;
    const int qb_w = blockIdx.y * 64 + qc * 32;
    if (kcol < SKV_) {
#pragma unroll
        for (int step = 0; step < 16; ++step) {
            const int q2 = step * 2 + hi;
            out1[((size_t)b * SQ_ + qb_w + q2) * SKV_ + kcol] = Trw[q2 * 33 + ql];
        }
    }
}

// ---------------------------------------------------------------------------
extern "C" void kernel_launch(void* const* d_in, const int* in_sizes, int n_in,
                              void* d_out, int out_size, void* d_ws, size_t ws_size,
                              hipStream_t stream) {
    const float* q   = (const float*)d_in[0];
    const float* kv  = (const float*)d_in[1];
    const void*  msk = d_in[2];
    const float* Wq  = (const float*)d_in[3];
    const float* bq  = (const float*)d_in[4];
    const float* Wk  = (const float*)d_in[5];
    const float* bk  = (const float*)d_in[6];
    const float* Wv  = (const float*)d_in[7];
    const float* bv  = (const float*)d_in[8];
    const float* Wo  = (const float*)d_in[9];
    const float* bo  = (const float*)d_in[10];

    char* ws = (char*)d_ws;
    // layout (bytes):
    unsigned short* qbf = (unsigned short*)(ws);              // 16,777,216 (aliased by OP later)
    unsigned short* OP  = (unsigned short*)(ws);              // alias: qbf dead after gemm Q
    unsigned short* kvbf= (unsigned short*)(ws + 16777216);   // 16,785,408
    unsigned short* Wqb = (unsigned short*)(ws + 33562624);   //  2,097,152
    unsigned short* Wkb = (unsigned short*)(ws + 35659776);   //  2,097,152
    unsigned short* Wvb = (unsigned short*)(ws + 37756928);   //  2,097,152
    unsigned short* Wob = (unsigned short*)(ws + 39854080);   //  2,097,152
    unsigned short* Qb  = (unsigned short*)(ws + 41951232);   // 16,777,216
    unsigned short* Kb  = (unsigned short*)(ws + 58728448);   // 17,039,360
    unsigned short* Vt  = (unsigned short*)(ws + 75767808);   // 17,039,360
    float*          Mst = (float*)(ws + 92807168);            //    524,288
    float*          Lst = (float*)(ws + 93331456);            //    524,288
    unsigned char* condm = (unsigned char*)(ws + 93855744);   //      8,192

    float* out0 = (float*)d_out;
    float* out1 = out0 + (size_t)SQ_ * B_ * E_;

    decode_mask_kernel<<<1, 256, 0, stream>>>(msk, condm);
    // bulk f32 -> bf16 conversions
    cvt_bf16_kernel<<<2048, 256, 0, stream>>>(q, qbf, (SQ_ * B_ * E_) / 8);
    cvt_bf16_kernel<<<2048, 256, 0, stream>>>(kv, kvbf, (SKV_ * B_ * E_) / 8);
    cvt_bf16_kernel<<<512, 256, 0, stream>>>(Wq, Wqb, (E_ * E_) / 8);
    cvt_bf16_kernel<<<512, 256, 0, stream>>>(Wk, Wkb, (E_ * E_) / 8);
    cvt_bf16_kernel<<<512, 256, 0, stream>>>(Wv, Wvb, (E_ * E_) / 8);
    cvt_bf16_kernel<<<512, 256, 0, stream>>>(Wo, Wob, (E_ * E_) / 8);
    // projections (128x128 tiles, chunked-XCD 1-D grid)
    gemm128_kernel<0><<<512, 256, 0, stream>>>(qbf, Wqb, bq, (void*)Qb, SQ_ * B_, 64);
    gemm128_kernel<1><<<576, 256, 0, stream>>>(kvbf, Wkb, bk, (void*)Kb, SKV_ * B_, 65);
    gemm128_kernel<2><<<576, 256, 0, stream>>>(kvbf, Wvb, bv, (void*)Vt, SKV_ * B_, 65);
    zero_pad_kernel<<<992, 256, 0, stream>>>(Kb, Vt);
    attn_fwd_kernel<<<dim3(16, 16, 4), 256, 0, stream>>>(Qb, Kb, Vt, condm, OP, Mst, Lst);
    attn_probs_kernel<<<dim3(33, 32, 4), 256, 0, stream>>>(Qb, Kb, Mst, Lst, condm, out1);
    gemm128_kernel<3><<<512, 256, 0, stream>>>(OP, Wob, bo, (void*)out0, SQ_ * B_, 64);
}

// Round 12
// 510.989 us; speedup vs baseline: 1.7218x; 1.0127x over previous
//
#include <hip/hip_runtime.h>
#include <hip/hip_bf16.h>

#define B_ 4
#define H_ 16
#define D_ 64
#define E_ 1024
#define SQ_ 2048
#define SKV_ 2049
#define SKVP_ 2080
#define QSCALE 0.18033688011112042f   /* (1/8) * log2(e) */

typedef __attribute__((ext_vector_type(8))) short short8;
typedef __attribute__((ext_vector_type(4))) float f32x4;
typedef __attribute__((ext_vector_type(16))) float f32x16;
typedef __attribute__((ext_vector_type(4))) unsigned int u32x4;
typedef __attribute__((ext_vector_type(4))) float float4v;

static __device__ __forceinline__ float ex2(float x) {
    return __builtin_amdgcn_exp2f(x);   // raw v_exp_f32 (2^x)
}

static __device__ __forceinline__ unsigned short f2bf(float f) {
    unsigned int u = __float_as_uint(f);
    u += 0x7FFFu + ((u >> 16) & 1u);
    return (unsigned short)(u >> 16);
}
// HW packed convert: v_cvt_pk_bf16_f32 (RNE), a -> low, b -> high
static __device__ __forceinline__ unsigned int pack2(float a, float b) {
    union { __hip_bfloat162 h; unsigned int u; } cv;
    cv.h = __float22bfloat162_rn(make_float2(a, b));
    return cv.u;
}

static __device__ __forceinline__ f32x4 mfma16(short8 a, short8 b, f32x4 c) {
    return __builtin_amdgcn_mfma_f32_16x16x32_bf16(a, b, c, 0, 0, 0);
}
static __device__ __forceinline__ f32x16 mfma32(short8 a, short8 b, f32x16 c) {
    return __builtin_amdgcn_mfma_f32_32x32x16_bf16(a, b, c, 0, 0, 0);
}

// ---------------------------------------------------------------------------
// f32 -> bf16 bulk convert (8 elems/thread/iter, grid-stride)
// ---------------------------------------------------------------------------
__global__ void cvt_bf16_kernel(const float* __restrict__ in,
                                unsigned short* __restrict__ out, int n8) {
    for (int i = blockIdx.x * blockDim.x + threadIdx.x; i < n8; i += gridDim.x * blockDim.x) {
        const float4v a = *(const float4v*)&in[(size_t)i * 8];
        const float4v b = *(const float4v*)&in[(size_t)i * 8 + 4];
        u32x4 o;
        o[0] = pack2(a[0], a[1]);
        o[1] = pack2(a[2], a[3]);
        o[2] = pack2(b[0], b[1]);
        o[3] = pack2(b[2], b[3]);
        *(u32x4*)&out[(size_t)i * 8] = o;
    }
}

// ---------------------------------------------------------------------------
// Mask decode: sniff dtype (uint8 bool vs int32/f32 0/1 words), write uint8.
// ---------------------------------------------------------------------------
__global__ void decode_mask_kernel(const void* __restrict__ mraw,
                                   unsigned char* __restrict__ condm) {
    __shared__ int flags[2];
    const int t = threadIdx.x;
    if (t < 2) flags[t] = 1;
    __syncthreads();
    const unsigned int* wp = (const unsigned int*)mraw;
    int okI = 1, okF = 1;
    for (int i = t; i < 2048; i += 256) {
        unsigned int w = wp[i];
        if (w > 1u) okI = 0;
        if (w != 0u && w != 0x3F800000u) okF = 0;
    }
    if (!okI) atomicAnd(&flags[0], 0);
    if (!okF) atomicAnd(&flags[1], 0);
    __syncthreads();
    const int isWord = flags[0] | flags[1];
    for (int i = t; i < B_ * SQ_; i += 256) {
        unsigned char v;
        if (isWord) v = (unsigned char)(wp[i] != 0u);
        else        v = (unsigned char)(((const unsigned char*)mraw)[i] != 0);
        condm[i] = v;
    }
}

// ---------------------------------------------------------------------------
// 128x128-tile GEMM: C = A @ W^T + bias, A and W pre-converted bf16.
// ---------------------------------------------------------------------------
template <int MODE>
__global__ __launch_bounds__(256, 2)
void gemm128_kernel(const unsigned short* __restrict__ Abf,
                    const unsigned short* __restrict__ Wbf,
                    const float* __restrict__ bias, void* __restrict__ Outp,
                    int nrows, int nrb) {
    const int bid = blockIdx.x;
    const int xcd = bid & 7;
    const int pos = bid >> 3;
    const int cb = pos & 7;
    const int rb = (pos >> 3) * 8 + xcd;
    if (rb >= nrb) return;
    const int row0 = rb * 128, col0 = cb * 128;

    __shared__ unsigned short As[128][40];
    __shared__ unsigned short Ws[128][40];
    const int t = threadIdx.x;
    const int w = t >> 6, lane = t & 63;
    const int wm = w >> 1, wn = w & 1;
    const int lr = lane & 15, lg = lane >> 4, lk = lg * 8;
    const int srow = t >> 1, sc0 = (t & 1) * 16;
    int ar = row0 + srow;
    if (ar >= nrows) ar = nrows - 1;
    const int wrow = col0 + srow;

    f32x4 acc[4][4] = {};

#pragma unroll 1
    for (int k0 = 0; k0 < E_; k0 += 32) {
        {
            const unsigned short* ap = &Abf[(size_t)ar * E_ + k0 + sc0];
            *(short8*)&As[srow][sc0] = *(const short8*)&ap[0];
            *(short8*)&As[srow][sc0 + 8] = *(const short8*)&ap[8];
        }
        {
            const unsigned short* wp2 = &Wbf[(size_t)wrow * E_ + k0 + sc0];
            *(short8*)&Ws[srow][sc0] = *(const short8*)&wp2[0];
            *(short8*)&Ws[srow][sc0 + 8] = *(const short8*)&wp2[8];
        }
        __syncthreads();
        short8 af[4], bf[4];
#pragma unroll
        for (int mi = 0; mi < 4; ++mi) af[mi] = *(const short8*)&As[wm * 64 + mi * 16 + lr][lk];
#pragma unroll
        for (int ni = 0; ni < 4; ++ni) bf[ni] = *(const short8*)&Ws[wn * 64 + ni * 16 + lr][lk];
#pragma unroll
        for (int mi = 0; mi < 4; ++mi)
#pragma unroll
            for (int ni = 0; ni < 4; ++ni)
                acc[mi][ni] = mfma16(af[mi], bf[ni], acc[mi][ni]);
        __syncthreads();
    }

#pragma unroll
    for (int ni = 0; ni < 4; ++ni) {
        const int c = col0 + wn * 64 + ni * 16 + lr;
        const float bv = bias[c];
        const int h = c >> 6, d = c & 63;
#pragma unroll
        for (int mi = 0; mi < 4; ++mi) {
#pragma unroll
            for (int r4 = 0; r4 < 4; ++r4) {
                const int r = row0 + wm * 64 + mi * 16 + lg * 4 + r4;
                if (r >= nrows) continue;
                float v = acc[mi][ni][r4] + bv;
                if constexpr (MODE == 0) {
                    v *= QSCALE;
                    const int sq = r >> 2, b = r & 3;
                    ((unsigned short*)Outp)[(((size_t)(b * H_ + h) * SQ_) + sq) * D_ + d] = f2bf(v);
                } else if constexpr (MODE == 1) {
                    const int kvi = r >> 2, b = r & 3;
                    ((unsigned short*)Outp)[(((size_t)(b * H_ + h) * SKVP_) + kvi) * D_ + d] = f2bf(v);
                } else if constexpr (MODE == 2) {
                    const int kvi = r >> 2, b = r & 3;
                    ((unsigned short*)Outp)[(((size_t)(b * H_ + h) * D_) + d) * SKVP_ + kvi] = f2bf(v);
                } else {
                    ((float*)Outp)[(size_t)r * E_ + c] = v;
                }
            }
        }
    }
}

// ---------------------------------------------------------------------------
// Zero the kv padding rows/cols (2049..2079) of K and V^T.
// ---------------------------------------------------------------------------
__global__ void zero_pad_kernel(unsigned short* __restrict__ Kb,
                                unsigned short* __restrict__ Vt) {
    const int idx = blockIdx.x * blockDim.x + threadIdx.x;
    const int NK = 64 * 31 * 64;
    if (idx < NK) {
        const int bh = idx / (31 * 64);
        const int rem = idx - bh * 31 * 64;
        const int kvi = SKV_ + rem / 64;
        const int d = rem & 63;
        Kb[((size_t)bh * SKVP_ + kvi) * D_ + d] = 0;
    } else {
        const int j = idx - NK;
        if (j < 4096 * 31) {
            const int row = j / 31;
            const int kvi = SKV_ + (j - row * 31);
            Vt[(size_t)row * SKVP_ + kvi] = 0;
        }
    }
}

// ---------------------------------------------------------------------------
// Flash attention fwd, swapped-operand 32x32, exp2 domain, KV-tile 64,
// defer-max, ping-pong double-buffered K/V staging (1 barrier per tile).
// ---------------------------------------------------------------------------
__global__ __launch_bounds__(256, 4)
void attn_fwd_kernel(const unsigned short* __restrict__ Qb, const unsigned short* __restrict__ Kb,
                     const unsigned short* __restrict__ Vt, const unsigned char* __restrict__ condm,
                     unsigned short* __restrict__ OP, float* __restrict__ Mst,
                     float* __restrict__ Lst) {
    const int h = blockIdx.y, b = blockIdx.z;
    const int bh = b * H_ + h;
    const int t = threadIdx.x, w = t >> 6, lane = t & 63;
    const int ql = lane & 31;
    const int hi = lane >> 5;
    const int qg = blockIdx.x * 128 + w * 32 + ql;

    __shared__ unsigned short Ks[2 * 64 * 64];   // 2 buffers, XOR-swizzled
    __shared__ unsigned short Vs[2][64][72];     // 2 buffers, padded rows
    __shared__ unsigned int cjb[66];

    for (int g = t; g < 66; g += 256) {
        unsigned int wbits = 0;
        const int base = g * 32;
#pragma unroll 4
        for (int i = 0; i < 32; ++i) {
            const int kv = base + i;
            if (kv >= 1 && kv < SKV_) wbits |= ((unsigned int)condm[b * SQ_ + kv - 1]) << i;
        }
        cjb[g] = wbits;
    }

    const size_t qoff = ((size_t)bh * SQ_ + qg) * D_;
    short8 qf[4];
#pragma unroll
    for (int tt = 0; tt < 4; ++tt) qf[tt] = *(const short8*)&Qb[qoff + tt * 16 + hi * 8];

    const unsigned int ci = condm[b * SQ_ + qg];

    float m = -__builtin_inff(), l = 0.f;
    f32x16 o0 = {}, o1 = {};

    const int krow = t >> 2, kseg2 = (t & 3) * 2;   // K staging: 64 rows x 2 granules
    const int vrow = t >> 2, vc0 = (t & 3) * 16;    // V staging: 64 rows x 2 short8
    const unsigned short* Kbase = &Kb[(size_t)bh * SKVP_ * D_];
    const unsigned short* Vbase = &Vt[(size_t)bh * D_ * SKVP_];

    // prologue: stage tile 0 into buffer 0
    {
        const unsigned short* kp = &Kbase[(size_t)krow * D_];
        const short8 k0 = *(const short8*)&kp[kseg2 * 8];
        const short8 k1 = *(const short8*)&kp[(kseg2 + 1) * 8];
        const unsigned short* vp = &Vbase[(size_t)vrow * SKVP_];
        const short8 v0 = *(const short8*)&vp[vc0];
        const short8 v1 = *(const short8*)&vp[vc0 + 8];
        *(short8*)&Ks[krow * 64 + ((kseg2 ^ (krow & 7)) * 8)] = k0;
        *(short8*)&Ks[krow * 64 + (((kseg2 + 1) ^ (krow & 7)) * 8)] = k1;
        *(short8*)&Vs[0][vrow][vc0] = v0;
        *(short8*)&Vs[0][vrow][vc0 + 8] = v1;
    }
    __syncthreads();

#pragma unroll 1
    for (int it = 0; it < 33; ++it) {
        const int buf = it & 1;
        const int kv0 = it * 64;
        // issue next tile's global loads early (latency hides under compute)
        short8 nk0, nk1, nv0, nv1;
        if (it < 32) {
            const int kvn = kv0 + 64;
            int krg = kvn + krow;
            if (krg > SKVP_ - 1) krg = SKVP_ - 1;
            const unsigned short* kp = &Kbase[(size_t)krg * D_];
            nk0 = *(const short8*)&kp[kseg2 * 8];
            nk1 = *(const short8*)&kp[(kseg2 + 1) * 8];
            int vc = kvn + vc0;
            if (vc > SKVP_ - 8) vc = SKVP_ - 8;
            int vc2 = kvn + vc0 + 8;
            if (vc2 > SKVP_ - 8) vc2 = SKVP_ - 8;
            const unsigned short* vp = &Vbase[(size_t)vrow * SKVP_];
            nv0 = *(const short8*)&vp[vc];
            nv1 = *(const short8*)&vp[vc2];
        }

        const unsigned short* Ksb = &Ks[buf * 4096];
#pragma unroll
        for (int ksub = 0; ksub < 2; ++ksub) {
            const int kvg = kv0 + ksub * 32;
            // S^T = K @ Q^T  (col = q = ql, row = k)
            f32x16 S = {};
#pragma unroll
            for (int tt = 0; tt < 4; ++tt) {
                const short8 kf = *(const short8*)&Ksb[(ksub * 32 + ql) * 64 + (((2 * tt + hi) ^ (ql & 7)) * 8)];
                S = mfma32(kf, qf[tt], S);
            }

            const unsigned int cjw = cjb[kvg >> 5];
            const int T = qg + 1 - kvg;
            unsigned int causalw;
            if (T < 0) causalw = ~0u;
            else if (T >= 31) causalw = 0u;
            else causalw = (~0u) << (T + 1);
            unsigned int mb = ci ? ~cjw : causalw;
            if (kvg == 0) mb &= ~1u;     // text column always visible
            const unsigned int mbs = mb >> (hi * 4);

#pragma unroll
            for (int r = 0; r < 16; ++r) {
                const int kc = (r & 3) + 8 * (r >> 2);
                S[r] = ((mbs >> kc) & 1u) ? -__builtin_inff() : S[r];
            }
            float t0 = fmaxf(fmaxf(S[0], S[1]), S[2]);
            float t1 = fmaxf(fmaxf(S[3], S[4]), S[5]);
            float t2 = fmaxf(fmaxf(S[6], S[7]), S[8]);
            float t3 = fmaxf(fmaxf(S[9], S[10]), S[11]);
            float t4 = fmaxf(fmaxf(S[12], S[13]), S[14]);
            float rmax = fmaxf(fmaxf(fmaxf(t0, t1), t2), fmaxf(fmaxf(t3, t4), S[15]));
            rmax = fmaxf(rmax, __shfl_xor(rmax, 32));

            if (!__all(rmax <= m + 8.0f)) {
                const float mn = fmaxf(m, rmax);
                const float alpha = ex2(m - mn);
                l *= alpha;
                o0 *= alpha;
                o1 *= alpha;
                m = mn;
            }

#pragma unroll
            for (int r = 0; r < 16; ++r) S[r] = ex2(S[r] - m);   // exp2(-inf)=0
            const float a0s = (S[0] + S[1]) + (S[2] + S[3]);
            const float a1s = (S[4] + S[5]) + (S[6] + S[7]);
            const float a2s = (S[8] + S[9]) + (S[10] + S[11]);
            const float a3s = (S[12] + S[13]) + (S[14] + S[15]);
            float psum = (a0s + a1s) + (a2s + a3s);
            psum += __shfl_xor(psum, 32);
            l += psum;

            const unsigned int w0 = pack2(S[0], S[1]);
            const unsigned int w1 = pack2(S[2], S[3]);
            const unsigned int w2 = pack2(S[4], S[5]);
            const unsigned int w3 = pack2(S[6], S[7]);
            const unsigned int w4 = pack2(S[8], S[9]);
            const unsigned int w5 = pack2(S[10], S[11]);
            const unsigned int w6 = pack2(S[12], S[13]);
            const unsigned int w7 = pack2(S[14], S[15]);
            const unsigned int x0 = __shfl_xor(w0, 32);
            const unsigned int x1 = __shfl_xor(w1, 32);
            const unsigned int x2 = __shfl_xor(w2, 32);
            const unsigned int x3 = __shfl_xor(w3, 32);
            const unsigned int x4 = __shfl_xor(w4, 32);
            const unsigned int x5 = __shfl_xor(w5, 32);
            const unsigned int x6 = __shfl_xor(w6, 32);
            const unsigned int x7 = __shfl_xor(w7, 32);
            union { u32x4 u; short8 s8; } pb0, pb1;
            pb0.u = (u32x4){hi ? x2 : w0, hi ? x3 : w1, hi ? w2 : x0, hi ? w3 : x1};
            pb1.u = (u32x4){hi ? x6 : w4, hi ? x7 : w5, hi ? w6 : x4, hi ? w7 : x5};

            const short8 vf00 = *(const short8*)&Vs[buf][ql][ksub * 32 + hi * 8];
            const short8 vf01 = *(const short8*)&Vs[buf][ql][ksub * 32 + 16 + hi * 8];
            const short8 vf10 = *(const short8*)&Vs[buf][32 + ql][ksub * 32 + hi * 8];
            const short8 vf11 = *(const short8*)&Vs[buf][32 + ql][ksub * 32 + 16 + hi * 8];
            o0 = mfma32(vf00, pb0.s8, o0);
            o0 = mfma32(vf01, pb1.s8, o0);
            o1 = mfma32(vf10, pb0.s8, o1);
            o1 = mfma32(vf11, pb1.s8, o1);
        }

        // write next tile into the other buffer (current buf still being read is untouched)
        if (it < 32) {
            const int nb = (buf ^ 1) * 4096;
            *(short8*)&Ks[nb + krow * 64 + ((kseg2 ^ (krow & 7)) * 8)] = nk0;
            *(short8*)&Ks[nb + krow * 64 + (((kseg2 + 1) ^ (krow & 7)) * 8)] = nk1;
            *(short8*)&Vs[buf ^ 1][vrow][vc0] = nv0;
            *(short8*)&Vs[buf ^ 1][vrow][vc0 + 8] = nv1;
        }
        __syncthreads();
    }

    const float linv = 1.0f / l;
    unsigned short* opbase = &OP[((size_t)qg * B_ + b) * E_ + h * D_];
#pragma unroll
    for (int rp = 0; rp < 8; ++rp) {
        const int r0 = rp * 2, r1 = r0 + 1;
        const int d = ((r0 & 3) + 8 * (r0 >> 2)) + 4 * hi;
        *(unsigned int*)(opbase + d) = pack2(o0[r0] * linv, o0[r1] * linv);
        *(unsigned int*)(opbase + 32 + d) = pack2(o1[r0] * linv, o1[r1] * linv);
    }
    if (hi == 0) {
        Mst[(size_t)bh * SQ_ + qg] = m;        // log2 domain
        Lst[(size_t)bh * SQ_ + qg] = linv;     // 1/l
    }
}

// ---------------------------------------------------------------------------
// attn-mean pass, swapped-operand 32x32 (exp2 domain), ping-pong K staging,
// XCD q-chunk swizzle: xcd owns q-blocks [xcd*4, xcd*4+4) for all (b,kv).
// ---------------------------------------------------------------------------
__global__ __launch_bounds__(256, 4)
void attn_probs_kernel(const unsigned short* __restrict__ Qb, const unsigned short* __restrict__ Kb,
                       const float* __restrict__ Mst, const float* __restrict__ Linv,
                       const unsigned char* __restrict__ condm, float* __restrict__ out1) {
    const int bid = blockIdx.x;
    const int xcd = bid & 7;
    const int pos = bid >> 3;        // 0..527
    const int qi = pos & 3;
    const int rest = pos >> 2;       // 0..131 = b*33 + kvb
    const int kvb = rest % 33;
    const int b = rest / 33;
    const int qblk = xcd * 4 + qi;   // 0..31
    const int kv0 = kvb * 64;

    const int t = threadIdx.x, w = t >> 6, lane = t & 63;
    const int ql = lane & 31, hi = lane >> 5;
    const int kc = w >> 1, qc = w & 1;
    const int qg = qblk * 64 + qc * 32 + ql;

    __shared__ char smem[17408];                 // Ks 2x8KB aliased with Tr 16.9KB
    unsigned short* Ks = (unsigned short*)smem;
    float* Tr = (float*)smem;
    __shared__ unsigned int cjw2[2];

    if (t < 64) {
        const int kvv = kv0 + t;
        int pred = 0;
        if (kvv >= 1 && kvv < SKV_) pred = condm[b * SQ_ + kvv - 1];
        const unsigned long long bal = __ballot(pred != 0);
        if (t == 0) { cjw2[0] = (unsigned int)bal; cjw2[1] = (unsigned int)(bal >> 32); }
    }
    const unsigned int ci = condm[b * SQ_ + qg];

    const int krow = t >> 2;
    const int kseg2 = (t & 3) * 2;
    int ksrc = kv0 + krow;
    if (ksrc >= SKVP_) ksrc = SKVP_ - 1;         // clamp into zeroed pad

    // prologue: stage head 0 into buffer 0
    {
        const unsigned short* kp = &Kb[((size_t)(b * H_) * SKVP_ + ksrc) * D_];
        const short8 k0 = *(const short8*)&kp[kseg2 * 8];
        const short8 k1 = *(const short8*)&kp[(kseg2 + 1) * 8];
        *(short8*)&Ks[krow * 64 + ((kseg2 ^ (krow & 7)) * 8)] = k0;
        *(short8*)&Ks[krow * 64 + (((kseg2 + 1) ^ (krow & 7)) * 8)] = k1;
    }
    __syncthreads();

    // per-lane mask word (cjw2 visible after the barrier)
    const int kvg = kv0 + kc * 32;
    unsigned int mb;
    {
        const unsigned int cjw = cjw2[kc];
        const int T = qg + 1 - kvg;
        unsigned int causalw;
        if (T < 0) causalw = ~0u;
        else if (T >= 31) causalw = 0u;
        else causalw = (~0u) << (T + 1);
        mb = ci ? ~cjw : causalw;
        if (kvg == 0) mb &= ~1u;                 // text column always visible
    }
    const unsigned int mbs = mb >> (hi * 4);

    float acc[16] = {};

#pragma unroll 1
    for (int h = 0; h < H_; ++h) {
        const int buf = h & 1;
        const int bh = b * H_ + h;
        // issue next head's K loads early
        short8 nk0, nk1;
        if (h < H_ - 1) {
            const unsigned short* kp = &Kb[((size_t)(bh + 1) * SKVP_ + ksrc) * D_];
            nk0 = *(const short8*)&kp[kseg2 * 8];
            nk1 = *(const short8*)&kp[(kseg2 + 1) * 8];
        }

        const size_t qoff = ((size_t)bh * SQ_ + qg) * D_;
        short8 qf[4];
#pragma unroll
        for (int tt = 0; tt < 4; ++tt) qf[tt] = *(const short8*)&Qb[qoff + tt * 16 + hi * 8];
        const float mh = Mst[(size_t)bh * SQ_ + qg];
        const float li = Linv[(size_t)bh * SQ_ + qg] * (1.0f / 16.0f);

        const unsigned short* Ksb = &Ks[buf * 4096];
        f32x16 S = {};
#pragma unroll
        for (int tt = 0; tt < 4; ++tt) {
            const short8 kf = *(const short8*)&Ksb[(kc * 32 + ql) * 64 + (((2 * tt + hi) ^ (ql & 7)) * 8)];
            S = mfma32(kf, qf[tt], S);
        }
#pragma unroll
        for (int r = 0; r < 16; ++r) {
            const int kk = (r & 3) + 8 * (r >> 2);
            const float p = ((mbs >> kk) & 1u) ? 0.f : ex2(S[r] - mh);
            acc[r] += p * li;
        }

        if (h < H_ - 1) {
            const int nb = (buf ^ 1) * 4096;
            *(short8*)&Ks[nb + krow * 64 + ((kseg2 ^ (krow & 7)) * 8)] = nk0;
            *(short8*)&Ks[nb + krow * 64 + (((kseg2 + 1) ^ (krow & 7)) * 8)] = nk1;
        }
        __syncthreads();
    }

    // epilogue: per-wave 32x32 transpose via LDS (aliases Ks), coalesced stores
    float* Trw = &Tr[w * (32 * 33)];
#pragma unroll
    for (int r = 0; r < 16; ++r) {
        const int kk = (r & 3) + 8 * (r >> 2) + 4 * hi;
        Trw[ql * 33 + kk] = acc[r];
    }
    const int kcol = kv0 + kc * 32 + ql;
    const int qb_w = qblk * 64 + qc * 32;
    if (kcol < SKV_) {
#pragma unroll
        for (int step = 0; step < 16; ++step) {
            const int q2 = step * 2 + hi;
            out1[((size_t)b * SQ_ + qb_w + q2) * SKV_ + kcol] = Trw[q2 * 33 + ql];
        }
    }
}

// ---------------------------------------------------------------------------
extern "C" void kernel_launch(void* const* d_in, const int* in_sizes, int n_in,
                              void* d_out, int out_size, void* d_ws, size_t ws_size,
                              hipStream_t stream) {
    const float* q   = (const float*)d_in[0];
    const float* kv  = (const float*)d_in[1];
    const void*  msk = d_in[2];
    const float* Wq  = (const float*)d_in[3];
    const float* bq  = (const float*)d_in[4];
    const float* Wk  = (const float*)d_in[5];
    const float* bk  = (const float*)d_in[6];
    const float* Wv  = (const float*)d_in[7];
    const float* bv  = (const float*)d_in[8];
    const float* Wo  = (const float*)d_in[9];
    const float* bo  = (const float*)d_in[10];

    char* ws = (char*)d_ws;
    unsigned short* qbf = (unsigned short*)(ws);              // 16,777,216 (aliased by OP later)
    unsigned short* OP  = (unsigned short*)(ws);              // alias: qbf dead after gemm Q
    unsigned short* kvbf= (unsigned short*)(ws + 16777216);   // 16,785,408
    unsigned short* Wqb = (unsigned short*)(ws + 33562624);   //  2,097,152
    unsigned short* Wkb = (unsigned short*)(ws + 35659776);   //  2,097,152
    unsigned short* Wvb = (unsigned short*)(ws + 37756928);   //  2,097,152
    unsigned short* Wob = (unsigned short*)(ws + 39854080);   //  2,097,152
    unsigned short* Qb  = (unsigned short*)(ws + 41951232);   // 16,777,216
    unsigned short* Kb  = (unsigned short*)(ws + 58728448);   // 17,039,360
    unsigned short* Vt  = (unsigned short*)(ws + 75767808);   // 17,039,360
    float*          Mst = (float*)(ws + 92807168);            //    524,288
    float*          Lst = (float*)(ws + 93331456);            //    524,288
    unsigned char* condm = (unsigned char*)(ws + 93855744);   //      8,192

    float* out0 = (float*)d_out;
    float* out1 = out0 + (size_t)SQ_ * B_ * E_;

    decode_mask_kernel<<<1, 256, 0, stream>>>(msk, condm);
    cvt_bf16_kernel<<<2048, 256, 0, stream>>>(q, qbf, (SQ_ * B_ * E_) / 8);
    cvt_bf16_kernel<<<2048, 256, 0, stream>>>(kv, kvbf, (SKV_ * B_ * E_) / 8);
    cvt_bf16_kernel<<<512, 256, 0, stream>>>(Wq, Wqb, (E_ * E_) / 8);
    cvt_bf16_kernel<<<512, 256, 0, stream>>>(Wk, Wkb, (E_ * E_) / 8);
    cvt_bf16_kernel<<<512, 256, 0, stream>>>(Wv, Wvb, (E_ * E_) / 8);
    cvt_bf16_kernel<<<512, 256, 0, stream>>>(Wo, Wob, (E_ * E_) / 8);
    gemm128_kernel<0><<<512, 256, 0, stream>>>(qbf, Wqb, bq, (void*)Qb, SQ_ * B_, 64);
    gemm128_kernel<1><<<576, 256, 0, stream>>>(kvbf, Wkb, bk, (void*)Kb, SKV_ * B_, 65);
    gemm128_kernel<2><<<576, 256, 0, stream>>>(kvbf, Wvb, bv, (void*)Vt, SKV_ * B_, 65);
    zero_pad_kernel<<<992, 256, 0, stream>>>(Kb, Vt);
    attn_fwd_kernel<<<dim3(16, 16, 4), 256, 0, stream>>>(Qb, Kb, Vt, condm, OP, Mst, Lst);
    attn_probs_kernel<<<4224, 256, 0, stream>>>(Qb, Kb, Mst, Lst, condm, out1);
    gemm128_kernel<3><<<512, 256, 0, stream>>>(OP, Wob, bo, (void*)out0, SQ_ * B_, 64);
}

// Round 14
// 453.561 us; speedup vs baseline: 1.9398x; 1.1266x over previous
//
#include <hip/hip_runtime.h>
#include <hip/hip_bf16.h>

#define B_ 4
#define H_ 16
#define D_ 64
#define E_ 1024
#define SQ_ 2048
#define SKV_ 2049
#define SKVP_ 2080
#define QSCALE 0.18033688011112042f   /* (1/8) * log2(e) */

typedef __attribute__((ext_vector_type(8))) short short8;
typedef __attribute__((ext_vector_type(4))) float f32x4;
typedef __attribute__((ext_vector_type(16))) float f32x16;
typedef __attribute__((ext_vector_type(4))) unsigned int u32x4;
typedef __attribute__((ext_vector_type(4))) float float4v;

static __device__ __forceinline__ float ex2(float x) {
    return __builtin_amdgcn_exp2f(x);   // raw v_exp_f32 (2^x)
}

static __device__ __forceinline__ unsigned short f2bf(float f) {
    unsigned int u = __float_as_uint(f);
    u += 0x7FFFu + ((u >> 16) & 1u);
    return (unsigned short)(u >> 16);
}
static __device__ __forceinline__ unsigned int pack2(float a, float b) {
    union { __hip_bfloat162 h; unsigned int u; } cv;
    cv.h = __float22bfloat162_rn(make_float2(a, b));
    return cv.u;
}

static __device__ __forceinline__ f32x4 mfma16(short8 a, short8 b, f32x4 c) {
    return __builtin_amdgcn_mfma_f32_16x16x32_bf16(a, b, c, 0, 0, 0);
}
static __device__ __forceinline__ f32x16 mfma32(short8 a, short8 b, f32x16 c) {
    return __builtin_amdgcn_mfma_f32_32x32x16_bf16(a, b, c, 0, 0, 0);
}

// async global -> LDS, 16B per lane (wave-uniform LDS base + lane*16)
static __device__ __forceinline__ void gload16(const void* g, void* l) {
    __builtin_amdgcn_global_load_lds(
        (const __attribute__((address_space(1))) unsigned int*)g,
        (__attribute__((address_space(3))) unsigned int*)l, 16, 0, 0);
}

// ---------------------------------------------------------------------------
// f32 -> bf16 bulk convert (8 elems/thread/iter, grid-stride)
// ---------------------------------------------------------------------------
__global__ void cvt_bf16_kernel(const float* __restrict__ in,
                                unsigned short* __restrict__ out, int n8) {
    for (int i = blockIdx.x * blockDim.x + threadIdx.x; i < n8; i += gridDim.x * blockDim.x) {
        const float4v a = *(const float4v*)&in[(size_t)i * 8];
        const float4v b = *(const float4v*)&in[(size_t)i * 8 + 4];
        u32x4 o;
        o[0] = pack2(a[0], a[1]);
        o[1] = pack2(a[2], a[3]);
        o[2] = pack2(b[0], b[1]);
        o[3] = pack2(b[2], b[3]);
        *(u32x4*)&out[(size_t)i * 8] = o;
    }
}

// ---------------------------------------------------------------------------
// Mask decode: sniff dtype (uint8 bool vs int32/f32 0/1 words), write uint8.
// ---------------------------------------------------------------------------
__global__ void decode_mask_kernel(const void* __restrict__ mraw,
                                   unsigned char* __restrict__ condm) {
    __shared__ int flags[2];
    const int t = threadIdx.x;
    if (t < 2) flags[t] = 1;
    __syncthreads();
    const unsigned int* wp = (const unsigned int*)mraw;
    int okI = 1, okF = 1;
    for (int i = t; i < 2048; i += 256) {
        unsigned int w = wp[i];
        if (w > 1u) okI = 0;
        if (w != 0u && w != 0x3F800000u) okF = 0;
    }
    if (!okI) atomicAnd(&flags[0], 0);
    if (!okF) atomicAnd(&flags[1], 0);
    __syncthreads();
    const int isWord = flags[0] | flags[1];
    for (int i = t; i < B_ * SQ_; i += 256) {
        unsigned char v;
        if (isWord) v = (unsigned char)(wp[i] != 0u);
        else        v = (unsigned char)(((const unsigned char*)mraw)[i] != 0);
        condm[i] = v;
    }
}

// ---------------------------------------------------------------------------
// 128x128-tile GEMM, m97 structure: 8 waves (2x4), linear LDS [128][32],
// global_load_lds(16B) staging, 2-barrier K-loop. A and W bf16.
// MODE 0: Q out (x QSCALE), 1: K out, 2: V^T out, 3: f32 out rows (sq,b).
// ---------------------------------------------------------------------------
template <int MODE>
__global__ __launch_bounds__(512, 2)
void gemm128_kernel(const unsigned short* __restrict__ Abf,
                    const unsigned short* __restrict__ Wbf,
                    const float* __restrict__ bias, void* __restrict__ Outp,
                    int nrows, int nrb) {
    const int bid = blockIdx.x;
    const int xcd = bid & 7;
    const int pos = bid >> 3;
    const int cb = pos & 7;
    const int rb = (pos >> 3) * 8 + xcd;
    if (rb >= nrb) return;
    const int row0 = rb * 128, col0 = cb * 128;

    __shared__ unsigned short As[128 * 32];
    __shared__ unsigned short Ws[128 * 32];
    const int t = threadIdx.x;
    const int w = t >> 6, lane = t & 63;
    const int wm = w >> 2, wn = w & 3;           // 2 x 4 wave grid, 64x32 each
    const int lr = lane & 15, lg = lane >> 4, lk = lg * 8;

    const int srow = w * 16 + (lane >> 2);
    const int scol = (lane & 3) * 8;
    int ar = row0 + srow;
    if (ar >= nrows) ar = nrows - 1;
    const int wrow = col0 + srow;                // always < 1024
    const unsigned short* agp = &Abf[(size_t)ar * E_ + scol];
    const unsigned short* wgp = &Wbf[(size_t)wrow * E_ + scol];
    unsigned short* lAs = &As[(size_t)w * 512 + (size_t)lane * 8];
    unsigned short* lWs = &Ws[(size_t)w * 512 + (size_t)lane * 8];

    f32x4 acc[4][2] = {};

#pragma unroll 1
    for (int k0 = 0; k0 < E_; k0 += 32) {
        gload16(agp + k0, lAs);
        gload16(wgp + k0, lWs);
        __syncthreads();
        short8 af[4], bf2[2];
#pragma unroll
        for (int mi = 0; mi < 4; ++mi)
            af[mi] = *(const short8*)&As[(wm * 64 + mi * 16 + lr) * 32 + lk];
#pragma unroll
        for (int ni = 0; ni < 2; ++ni)
            bf2[ni] = *(const short8*)&Ws[(wn * 32 + ni * 16 + lr) * 32 + lk];
#pragma unroll
        for (int mi = 0; mi < 4; ++mi)
#pragma unroll
            for (int ni = 0; ni < 2; ++ni)
                acc[mi][ni] = mfma16(af[mi], bf2[ni], acc[mi][ni]);
        __syncthreads();
    }

#pragma unroll
    for (int ni = 0; ni < 2; ++ni) {
        const int c = col0 + wn * 32 + ni * 16 + lr;
        const float bv = bias[c];
        const int h = c >> 6, d = c & 63;
#pragma unroll
        for (int mi = 0; mi < 4; ++mi) {
#pragma unroll
            for (int r4 = 0; r4 < 4; ++r4) {
                const int r = row0 + wm * 64 + mi * 16 + lg * 4 + r4;
                if (r >= nrows) continue;
                float v = acc[mi][ni][r4] + bv;
                if constexpr (MODE == 0) {
                    v *= QSCALE;
                    const int sq = r >> 2, b = r & 3;
                    ((unsigned short*)Outp)[(((size_t)(b * H_ + h) * SQ_) + sq) * D_ + d] = f2bf(v);
                } else if constexpr (MODE == 1) {
                    const int kvi = r >> 2, b = r & 3;
                    ((unsigned short*)Outp)[(((size_t)(b * H_ + h) * SKVP_) + kvi) * D_ + d] = f2bf(v);
                } else if constexpr (MODE == 2) {
                    const int kvi = r >> 2, b = r & 3;
                    ((unsigned short*)Outp)[(((size_t)(b * H_ + h) * D_) + d) * SKVP_ + kvi] = f2bf(v);
                } else {
                    ((float*)Outp)[(size_t)r * E_ + c] = v;
                }
            }
        }
    }
}

// ---------------------------------------------------------------------------
// Zero the kv padding rows/cols (2049..2079) of K and V^T.
// ---------------------------------------------------------------------------
__global__ void zero_pad_kernel(unsigned short* __restrict__ Kb,
                                unsigned short* __restrict__ Vt) {
    const int idx = blockIdx.x * blockDim.x + threadIdx.x;
    const int NK = 64 * 31 * 64;
    if (idx < NK) {
        const int bh = idx / (31 * 64);
        const int rem = idx - bh * 31 * 64;
        const int kvi = SKV_ + rem / 64;
        const int d = rem & 63;
        Kb[((size_t)bh * SKVP_ + kvi) * D_ + d] = 0;
    } else {
        const int j = idx - NK;
        if (j < 4096 * 31) {
            const int row = j / 31;
            const int kvi = SKV_ + (j - row * 31);
            Vt[(size_t)row * SKVP_ + kvi] = 0;
        }
    }
}

// ---------------------------------------------------------------------------
// Flash attention fwd, swapped-operand 32x32, exp2 domain, KV-tile 64,
// defer-max, ping-pong K/V staging. Stores combined stat M' = m + log2(l) + 4.
// ---------------------------------------------------------------------------
__global__ __launch_bounds__(256, 4)
void attn_fwd_kernel(const unsigned short* __restrict__ Qb, const unsigned short* __restrict__ Kb,
                     const unsigned short* __restrict__ Vt, const unsigned char* __restrict__ condm,
                     unsigned short* __restrict__ OP, float* __restrict__ Mst) {
    const int h = blockIdx.y, b = blockIdx.z;
    const int bh = b * H_ + h;
    const int t = threadIdx.x, w = t >> 6, lane = t & 63;
    const int ql = lane & 31;
    const int hi = lane >> 5;
    const int qg = blockIdx.x * 128 + w * 32 + ql;

    __shared__ unsigned short Ks[2 * 64 * 64];   // 2 buffers, XOR-swizzled
    __shared__ unsigned short Vs[2][64][72];     // 2 buffers, padded rows
    __shared__ unsigned int cjb[66];

    for (int g = t; g < 66; g += 256) {
        unsigned int wbits = 0;
        const int base = g * 32;
#pragma unroll 4
        for (int i = 0; i < 32; ++i) {
            const int kv = base + i;
            if (kv >= 1 && kv < SKV_) wbits |= ((unsigned int)condm[b * SQ_ + kv - 1]) << i;
        }
        cjb[g] = wbits;
    }

    const size_t qoff = ((size_t)bh * SQ_ + qg) * D_;
    short8 qf[4];
#pragma unroll
    for (int tt = 0; tt < 4; ++tt) qf[tt] = *(const short8*)&Qb[qoff + tt * 16 + hi * 8];

    const unsigned int ci = condm[b * SQ_ + qg];

    float m = -__builtin_inff(), l = 0.f;
    f32x16 o0 = {}, o1 = {};

    const int krow = t >> 2, kseg2 = (t & 3) * 2;
    const int vrow = t >> 2, vc0 = (t & 3) * 16;
    const unsigned short* Kbase = &Kb[(size_t)bh * SKVP_ * D_];
    const unsigned short* Vbase = &Vt[(size_t)bh * D_ * SKVP_];

    {
        const unsigned short* kp = &Kbase[(size_t)krow * D_];
        const short8 k0 = *(const short8*)&kp[kseg2 * 8];
        const short8 k1 = *(const short8*)&kp[(kseg2 + 1) * 8];
        const unsigned short* vp = &Vbase[(size_t)vrow * SKVP_];
        const short8 v0 = *(const short8*)&vp[vc0];
        const short8 v1 = *(const short8*)&vp[vc0 + 8];
        *(short8*)&Ks[krow * 64 + ((kseg2 ^ (krow & 7)) * 8)] = k0;
        *(short8*)&Ks[krow * 64 + (((kseg2 + 1) ^ (krow & 7)) * 8)] = k1;
        *(short8*)&Vs[0][vrow][vc0] = v0;
        *(short8*)&Vs[0][vrow][vc0 + 8] = v1;
    }
    __syncthreads();

#pragma unroll 1
    for (int it = 0; it < 33; ++it) {
        const int buf = it & 1;
        const int kv0 = it * 64;
        short8 nk0, nk1, nv0, nv1;
        if (it < 32) {
            const int kvn = kv0 + 64;
            int krg = kvn + krow;
            if (krg > SKVP_ - 1) krg = SKVP_ - 1;
            const unsigned short* kp = &Kbase[(size_t)krg * D_];
            nk0 = *(const short8*)&kp[kseg2 * 8];
            nk1 = *(const short8*)&kp[(kseg2 + 1) * 8];
            int vc = kvn + vc0;
            if (vc > SKVP_ - 8) vc = SKVP_ - 8;
            int vc2 = kvn + vc0 + 8;
            if (vc2 > SKVP_ - 8) vc2 = SKVP_ - 8;
            const unsigned short* vp = &Vbase[(size_t)vrow * SKVP_];
            nv0 = *(const short8*)&vp[vc];
            nv1 = *(const short8*)&vp[vc2];
        }

        const unsigned short* Ksb = &Ks[buf * 4096];
#pragma unroll
        for (int ksub = 0; ksub < 2; ++ksub) {
            const int kvg = kv0 + ksub * 32;
            f32x16 S = {};
#pragma unroll
            for (int tt = 0; tt < 4; ++tt) {
                const short8 kf = *(const short8*)&Ksb[(ksub * 32 + ql) * 64 + (((2 * tt + hi) ^ (ql & 7)) * 8)];
                S = mfma32(kf, qf[tt], S);
            }

            const unsigned int cjw = cjb[kvg >> 5];
            const int T = qg + 1 - kvg;
            unsigned int causalw;
            if (T < 0) causalw = ~0u;
            else if (T >= 31) causalw = 0u;
            else causalw = (~0u) << (T + 1);
            unsigned int mb = ci ? ~cjw : causalw;
            if (kvg == 0) mb &= ~1u;
            const unsigned int mbs = mb >> (hi * 4);

#pragma unroll
            for (int r = 0; r < 16; ++r) {
                const int kc = (r & 3) + 8 * (r >> 2);
                S[r] = ((mbs >> kc) & 1u) ? -__builtin_inff() : S[r];
            }
            float t0 = fmaxf(fmaxf(S[0], S[1]), S[2]);
            float t1 = fmaxf(fmaxf(S[3], S[4]), S[5]);
            float t2 = fmaxf(fmaxf(S[6], S[7]), S[8]);
            float t3 = fmaxf(fmaxf(S[9], S[10]), S[11]);
            float t4 = fmaxf(fmaxf(S[12], S[13]), S[14]);
            float rmax = fmaxf(fmaxf(fmaxf(t0, t1), t2), fmaxf(fmaxf(t3, t4), S[15]));
            rmax = fmaxf(rmax, __shfl_xor(rmax, 32));

            if (!__all(rmax <= m + 8.0f)) {
                const float mn = fmaxf(m, rmax);
                const float alpha = ex2(m - mn);
                l *= alpha;
                o0 *= alpha;
                o1 *= alpha;
                m = mn;
            }

#pragma unroll
            for (int r = 0; r < 16; ++r) S[r] = ex2(S[r] - m);
            const float a0s = (S[0] + S[1]) + (S[2] + S[3]);
            const float a1s = (S[4] + S[5]) + (S[6] + S[7]);
            const float a2s = (S[8] + S[9]) + (S[10] + S[11]);
            const float a3s = (S[12] + S[13]) + (S[14] + S[15]);
            float psum = (a0s + a1s) + (a2s + a3s);
            psum += __shfl_xor(psum, 32);
            l += psum;

            const unsigned int w0 = pack2(S[0], S[1]);
            const unsigned int w1 = pack2(S[2], S[3]);
            const unsigned int w2 = pack2(S[4], S[5]);
            const unsigned int w3 = pack2(S[6], S[7]);
            const unsigned int w4 = pack2(S[8], S[9]);
            const unsigned int w5 = pack2(S[10], S[11]);
            const unsigned int w6 = pack2(S[12], S[13]);
            const unsigned int w7 = pack2(S[14], S[15]);
            const unsigned int x0 = __shfl_xor(w0, 32);
            const unsigned int x1 = __shfl_xor(w1, 32);
            const unsigned int x2 = __shfl_xor(w2, 32);
            const unsigned int x3 = __shfl_xor(w3, 32);
            const unsigned int x4 = __shfl_xor(w4, 32);
            const unsigned int x5 = __shfl_xor(w5, 32);
            const unsigned int x6 = __shfl_xor(w6, 32);
            const unsigned int x7 = __shfl_xor(w7, 32);
            union { u32x4 u; short8 s8; } pb0, pb1;
            pb0.u = (u32x4){hi ? x2 : w0, hi ? x3 : w1, hi ? w2 : x0, hi ? w3 : x1};
            pb1.u = (u32x4){hi ? x6 : w4, hi ? x7 : w5, hi ? w6 : x4, hi ? w7 : x5};

            const short8 vf00 = *(const short8*)&Vs[buf][ql][ksub * 32 + hi * 8];
            const short8 vf01 = *(const short8*)&Vs[buf][ql][ksub * 32 + 16 + hi * 8];
            const short8 vf10 = *(const short8*)&Vs[buf][32 + ql][ksub * 32 + hi * 8];
            const short8 vf11 = *(const short8*)&Vs[buf][32 + ql][ksub * 32 + 16 + hi * 8];
            o0 = mfma32(vf00, pb0.s8, o0);
            o0 = mfma32(vf01, pb1.s8, o0);
            o1 = mfma32(vf10, pb0.s8, o1);
            o1 = mfma32(vf11, pb1.s8, o1);
        }

        if (it < 32) {
            const int nb = (buf ^ 1) * 4096;
            *(short8*)&Ks[nb + krow * 64 + ((kseg2 ^ (krow & 7)) * 8)] = nk0;
            *(short8*)&Ks[nb + krow * 64 + (((kseg2 + 1) ^ (krow & 7)) * 8)] = nk1;
            *(short8*)&Vs[buf ^ 1][vrow][vc0] = nv0;
            *(short8*)&Vs[buf ^ 1][vrow][vc0 + 8] = nv1;
        }
        __syncthreads();
    }

    const float linv = 1.0f / l;
    unsigned short* opbase = &OP[((size_t)qg * B_ + b) * E_ + h * D_];
#pragma unroll
    for (int rp = 0; rp < 8; ++rp) {
        const int r0 = rp * 2, r1 = r0 + 1;
        const int d = ((r0 & 3) + 8 * (r0 >> 2)) + 4 * hi;
        *(unsigned int*)(opbase + d) = pack2(o0[r0] * linv, o0[r1] * linv);
        *(unsigned int*)(opbase + 32 + d) = pack2(o1[r0] * linv, o1[r1] * linv);
    }
    if (hi == 0) {
        // combined stat for the probs pass: exp2(S - M') = exp2(S-m)/(16*l)
        Mst[(size_t)bh * SQ_ + qg] = m + __log2f(l) + 4.0f;
    }
}

// ---------------------------------------------------------------------------
// attn-mean pass: ping-pong K in LDS AND Q/stat in registers (2-head unroll).
// Per element: p = mask ? 0 : exp2(S - M'); acc += p.  XCD q-chunk swizzle.
// ---------------------------------------------------------------------------
__global__ __launch_bounds__(256, 4)
void attn_probs_kernel(const unsigned short* __restrict__ Qb, const unsigned short* __restrict__ Kb,
                       const float* __restrict__ Mstp,
                       const unsigned char* __restrict__ condm, float* __restrict__ out1) {
    const int bid = blockIdx.x;
    const int xcd = bid & 7;
    const int pos = bid >> 3;        // 0..527
    const int qi = pos & 3;
    const int rest = pos >> 2;       // 0..131 = b*33 + kvb
    const int kvb = rest % 33;
    const int b = rest / 33;
    const int qblk = xcd * 4 + qi;   // 0..31
    const int kv0 = kvb * 64;

    const int t = threadIdx.x, w = t >> 6, lane = t & 63;
    const int ql = lane & 31, hi = lane >> 5;
    const int kc = w >> 1, qc = w & 1;
    const int qg = qblk * 64 + qc * 32 + ql;

    __shared__ char smem[17408];                 // Ks 2x8KB aliased with Tr 16.9KB
    unsigned short* Ks = (unsigned short*)smem;
    float* Tr = (float*)smem;
    __shared__ unsigned int cjw2[2];

    if (t < 64) {
        const int kvv = kv0 + t;
        int pred = 0;
        if (kvv >= 1 && kvv < SKV_) pred = condm[b * SQ_ + kvv - 1];
        const unsigned long long bal = __ballot(pred != 0);
        if (t == 0) { cjw2[0] = (unsigned int)bal; cjw2[1] = (unsigned int)(bal >> 32); }
    }
    const unsigned int ci = condm[b * SQ_ + qg];

    const int krow = t >> 2;
    const int kseg2 = (t & 3) * 2;
    int ksrc = kv0 + krow;
    if (ksrc >= SKVP_) ksrc = SKVP_ - 1;

    // prologue: K[h=0] -> buf0; Q[0],M'[0] -> A registers
    {
        const unsigned short* kp = &Kb[((size_t)(b * H_) * SKVP_ + ksrc) * D_];
        const short8 k0 = *(const short8*)&kp[kseg2 * 8];
        const short8 k1 = *(const short8*)&kp[(kseg2 + 1) * 8];
        *(short8*)&Ks[krow * 64 + ((kseg2 ^ (krow & 7)) * 8)] = k0;
        *(short8*)&Ks[krow * 64 + (((kseg2 + 1) ^ (krow & 7)) * 8)] = k1;
    }
    short8 qfA[4], qfB[4];
    float mpA, mpB;
    {
        const size_t qoff = ((size_t)(b * H_) * SQ_ + qg) * D_;
#pragma unroll
        for (int tt = 0; tt < 4; ++tt) qfA[tt] = *(const short8*)&Qb[qoff + tt * 16 + hi * 8];
        mpA = Mstp[(size_t)(b * H_) * SQ_ + qg];
    }
    __syncthreads();

    const int kvg = kv0 + kc * 32;
    unsigned int mb;
    {
        const unsigned int cjw = cjw2[kc];
        const int T = qg + 1 - kvg;
        unsigned int causalw;
        if (T < 0) causalw = ~0u;
        else if (T >= 31) causalw = 0u;
        else causalw = (~0u) << (T + 1);
        mb = ci ? ~cjw : causalw;
        if (kvg == 0) mb &= ~1u;
    }
    const unsigned int mbs = mb >> (hi * 4);

    float acc[16] = {};

#pragma unroll 1
    for (int hp = 0; hp < 8; ++hp) {
        // ---- even head 2hp: compute buf0/qfA ; prefetch 2hp+1 -> buf1/qfB
        {
            const int bh1 = b * H_ + 2 * hp + 1;
            short8 nk0, nk1;
            {
                const unsigned short* kp = &Kb[((size_t)bh1 * SKVP_ + ksrc) * D_];
                nk0 = *(const short8*)&kp[kseg2 * 8];
                nk1 = *(const short8*)&kp[(kseg2 + 1) * 8];
            }
            {
                const size_t qoff = ((size_t)bh1 * SQ_ + qg) * D_;
#pragma unroll
                for (int tt = 0; tt < 4; ++tt) qfB[tt] = *(const short8*)&Qb[qoff + tt * 16 + hi * 8];
                mpB = Mstp[(size_t)bh1 * SQ_ + qg];
            }
            f32x16 S = {};
#pragma unroll
            for (int tt = 0; tt < 4; ++tt) {
                const short8 kf = *(const short8*)&Ks[(kc * 32 + ql) * 64 + (((2 * tt + hi) ^ (ql & 7)) * 8)];
                S = mfma32(kf, qfA[tt], S);
            }
#pragma unroll
            for (int r = 0; r < 16; ++r) {
                const int kk = (r & 3) + 8 * (r >> 2);
                acc[r] += ((mbs >> kk) & 1u) ? 0.f : ex2(S[r] - mpA);
            }
            *(short8*)&Ks[4096 + krow * 64 + ((kseg2 ^ (krow & 7)) * 8)] = nk0;
            *(short8*)&Ks[4096 + krow * 64 + (((kseg2 + 1) ^ (krow & 7)) * 8)] = nk1;
            __syncthreads();
        }
        // ---- odd head 2hp+1: compute buf1/qfB ; prefetch 2hp+2 -> buf0/qfA
        {
            short8 nk0, nk1;
            const bool more = (hp < 7);
            if (more) {
                const int bh2 = b * H_ + 2 * hp + 2;
                const unsigned short* kp = &Kb[((size_t)bh2 * SKVP_ + ksrc) * D_];
                nk0 = *(const short8*)&kp[kseg2 * 8];
                nk1 = *(const short8*)&kp[(kseg2 + 1) * 8];
                const size_t qoff = ((size_t)bh2 * SQ_ + qg) * D_;
#pragma unroll
                for (int tt = 0; tt < 4; ++tt) qfA[tt] = *(const short8*)&Qb[qoff + tt * 16 + hi * 8];
                mpA = Mstp[(size_t)bh2 * SQ_ + qg];
            }
            f32x16 S = {};
#pragma unroll
            for (int tt = 0; tt < 4; ++tt) {
                const short8 kf = *(const short8*)&Ks[4096 + (kc * 32 + ql) * 64 + (((2 * tt + hi) ^ (ql & 7)) * 8)];
                S = mfma32(kf, qfB[tt], S);
            }
#pragma unroll
            for (int r = 0; r < 16; ++r) {
                const int kk = (r & 3) + 8 * (r >> 2);
                acc[r] += ((mbs >> kk) & 1u) ? 0.f : ex2(S[r] - mpB);
            }
            if (more) {
                *(short8*)&Ks[krow * 64 + ((kseg2 ^ (krow & 7)) * 8)] = nk0;
                *(short8*)&Ks[krow * 64 + (((kseg2 + 1) ^ (krow & 7)) * 8)] = nk1;
            }
            __syncthreads();
        }
    }

    // epilogue: per-wave 32x32 transpose via LDS (aliases Ks), coalesced stores
    float* Trw = &Tr[w * (32 * 33)];
#pragma unroll
    for (int r = 0; r < 16; ++r) {
        const int kk = (r & 3) + 8 * (r >> 2) + 4 * hi;
        Trw[ql * 33 + kk] = acc[r];
    }
    const int kcol = kv0 + kc * 32 + ql;
    const int qb_w = qblk * 64 + qc * 32;
    if (kcol < SKV_) {
#pragma unroll
        for (int step = 0; step < 16; ++step) {
            const int q2 = step * 2 + hi;
            out1[((size_t)b * SQ_ + qb_w + q2) * SKV_ + kcol] = Trw[q2 * 33 + ql];
        }
    }
}

// ---------------------------------------------------------------------------
extern "C" void kernel_launch(void* const* d_in, const int* in_sizes, int n_in,
                              void* d_out, int out_size, void* d_ws, size_t ws_size,
                              hipStream_t stream) {
    const float* q   = (const float*)d_in[0];
    const float* kv  = (const float*)d_in[1];
    const void*  msk = d_in[2];
    const float* Wq  = (const float*)d_in[3];
    const float* bq  = (const float*)d_in[4];
    const float* Wk  = (const float*)d_in[5];
    const float* bk  = (const float*)d_in[6];
    const float* Wv  = (const float*)d_in[7];
    const float* bv  = (const float*)d_in[8];
    const float* Wo  = (const float*)d_in[9];
    const float* bo  = (const float*)d_in[10];

    char* ws = (char*)d_ws;
    unsigned short* qbf = (unsigned short*)(ws);              // 16,777,216 (aliased by OP later)
    unsigned short* OP  = (unsigned short*)(ws);              // alias: qbf dead after gemm Q
    unsigned short* kvbf= (unsigned short*)(ws + 16777216);   // 16,785,408
    unsigned short* Wqb = (unsigned short*)(ws + 33562624);   //  2,097,152
    unsigned short* Wkb = (unsigned short*)(ws + 35659776);   //  2,097,152
    unsigned short* Wvb = (unsigned short*)(ws + 37756928);   //  2,097,152
    unsigned short* Wob = (unsigned short*)(ws + 39854080);   //  2,097,152
    unsigned short* Qb  = (unsigned short*)(ws + 41951232);   // 16,777,216
    unsigned short* Kb  = (unsigned short*)(ws + 58728448);   // 17,039,360
    unsigned short* Vt  = (unsigned short*)(ws + 75767808);   // 17,039,360
    float*          Mst = (float*)(ws + 92807168);            //    524,288
    unsigned char* condm = (unsigned char*)(ws + 93855744);   //      8,192

    float* out0 = (float*)d_out;
    float* out1 = out0 + (size_t)SQ_ * B_ * E_;

    decode_mask_kernel<<<1, 256, 0, stream>>>(msk, condm);
    cvt_bf16_kernel<<<2048, 256, 0, stream>>>(q, qbf, (SQ_ * B_ * E_) / 8);
    cvt_bf16_kernel<<<2048, 256, 0, stream>>>(kv, kvbf, (SKV_ * B_ * E_) / 8);
    cvt_bf16_kernel<<<512, 256, 0, stream>>>(Wq, Wqb, (E_ * E_) / 8);
    cvt_bf16_kernel<<<512, 256, 0, stream>>>(Wk, Wkb, (E_ * E_) / 8);
    cvt_bf16_kernel<<<512, 256, 0, stream>>>(Wv, Wvb, (E_ * E_) / 8);
    cvt_bf16_kernel<<<512, 256, 0, stream>>>(Wo, Wob, (E_ * E_) / 8);
    gemm128_kernel<0><<<512, 512, 0, stream>>>(qbf, Wqb, bq, (void*)Qb, SQ_ * B_, 64);
    gemm128_kernel<1><<<576, 512, 0, stream>>>(kvbf, Wkb, bk, (void*)Kb, SKV_ * B_, 65);
    gemm128_kernel<2><<<576, 512, 0, stream>>>(kvbf, Wvb, bv, (void*)Vt, SKV_ * B_, 65);
    zero_pad_kernel<<<992, 256, 0, stream>>>(Kb, Vt);
    attn_fwd_kernel<<<dim3(16, 16, 4), 256, 0, stream>>>(Qb, Kb, Vt, condm, OP, Mst);
    attn_probs_kernel<<<4224, 256, 0, stream>>>(Qb, Kb, Mst, condm, out1);
    gemm128_kernel<3><<<512, 512, 0, stream>>>(OP, Wob, bo, (void*)out0, SQ_ * B_, 64);
}